// Round 6
// baseline (336.400 us; speedup 1.0000x reference)
//
#include <hip/hip_runtime.h>

// Problem constants (match reference)
#define D 128
#define H 8
#define DK 16
#define FFDIM 512
#define NTYPES 5
#define LN_EPS 1e-5f

typedef __bf16 bf16x8 __attribute__((ext_vector_type(8)));
typedef float f32x4 __attribute__((ext_vector_type(4)));
typedef unsigned short ushort_t;
typedef unsigned int uint_t;

__device__ inline ushort_t bfbits(float f) {
  __bf16 b = (__bf16)f;
  return __builtin_bit_cast(ushort_t, b);
}
__device__ inline float bf2f(ushort_t u) {
  return __uint_as_float(((uint_t)u) << 16);
}

// ---------------------------------------------------------------------------
// K0: detect mask dtype (byte-bool vs int32). flag=1 for byte masks.
// Parallel over 64 lanes (was a 1-thread serial pointer walk).
// ---------------------------------------------------------------------------
__global__ void detect_kernel(const unsigned char* __restrict__ m8, int E,
                              int* __restrict__ flag) {
  int lane = threadIdx.x;  // 64 threads, 1 wave
  int s = 1;
  if (lane < E) {
    s = 0;
#pragma unroll
    for (int i = 0; i < NTYPES; ++i) s += (m8[(size_t)i * E + lane] != 0);
  }
  unsigned long long b = __ballot(s == 1);
  if (lane == 0) *flag = (b == ~0ull) ? 1 : 0;
}

__device__ inline int decode_etype(const unsigned char* __restrict__ m8,
                                   int E, int e, int is8) {
  int t = 0;
  if (is8) {
#pragma unroll
    for (int i = 1; i < NTYPES; ++i) t += i * (m8[(size_t)i * E + e] != 0);
  } else {
    const int* m32 = (const int*)m8;
#pragma unroll
    for (int i = 1; i < NTYPES; ++i) t += i * (m32[(size_t)i * E + e] != 0);
  }
  return t > (NTYPES - 1) ? (NTYPES - 1) : t;
}

// ---------------------------------------------------------------------------
// K1: LayerNorm x -> z, stored as hi/lo bf16 split (parked in d_out)
// ---------------------------------------------------------------------------
__global__ __launch_bounds__(256) void ln1_kernel(
    const float* __restrict__ x, const float* __restrict__ g,
    const float* __restrict__ b, ushort_t* __restrict__ zh,
    ushort_t* __restrict__ zl, int n) {
  int row = blockIdx.x * 4 + (threadIdx.x >> 6);
  int lane = threadIdx.x & 63;
  if (row >= n) return;
  const float* xr = x + (size_t)row * D;
  float v0 = xr[lane], v1 = xr[lane + 64];
  float s = v0 + v1, ss = v0 * v0 + v1 * v1;
  for (int o = 32; o; o >>= 1) { s += __shfl_xor(s, o); ss += __shfl_xor(ss, o); }
  float mu = s * (1.f / D);
  float var = ss * (1.f / D) - mu * mu;
  float rs = rsqrtf(var + LN_EPS);
  float z0 = (v0 - mu) * rs * g[lane] + b[lane];
  float z1 = (v1 - mu) * rs * g[lane + 64] + b[lane + 64];
  size_t o0 = (size_t)row * D + lane, o1 = o0 + 64;
  __bf16 h0 = (__bf16)z0, h1 = (__bf16)z1;
  zh[o0] = __builtin_bit_cast(ushort_t, h0);
  zh[o1] = __builtin_bit_cast(ushort_t, h1);
  __bf16 l0 = (__bf16)(z0 - (float)h0), l1 = (__bf16)(z1 - (float)h1);
  zl[o0] = __builtin_bit_cast(ushort_t, l0);
  zl[o1] = __builtin_bit_cast(ushort_t, l1);
}

// ---------------------------------------------------------------------------
// K1b: convert a row-major f32 weight [K][N] into MFMA B-fragment order,
// hi/lo bf16 split.
// ---------------------------------------------------------------------------
__global__ void conv_frag_kernel(const float* __restrict__ W,
                                 ushort_t* __restrict__ hi,
                                 ushort_t* __restrict__ lo,
                                 int K, int Ncol, size_t matW, size_t matF) {
  int gid = blockIdx.x * 256 + threadIdx.x;
  int total = (Ncol / 16) * (K / 32) * 64;
  if (gid >= total) return;
  const float* Wm = W + (size_t)blockIdx.y * matW;
  ushort_t* him = hi + (size_t)blockIdx.y * matF;
  ushort_t* lom = lo + (size_t)blockIdx.y * matF;
  int l = gid & 63;
  int ck = gid >> 6;
  int kk = ck % (K / 32);
  int c = ck / (K / 32);
  int row0 = kk * 32 + (l >> 4) * 8;
  int col = c * 16 + (l & 15);
  size_t ob = (size_t)gid * 8;
#pragma unroll
  for (int j = 0; j < 8; ++j) {
    float w = Wm[(size_t)(row0 + j) * Ncol + col];
    __bf16 h = (__bf16)w;
    him[ob + j] = __builtin_bit_cast(ushort_t, h);
    __bf16 lo_ = (__bf16)(w - (float)h);
    lom[ob + j] = __builtin_bit_cast(ushort_t, lo_);
  }
}

// ---------------------------------------------------------------------------
// K2: proj via MFMA: P[t][node][d] = bf16( z @ Wk[t] + bk[t] )
// ---------------------------------------------------------------------------
__global__ __launch_bounds__(256, 3) void proj_mfma_kernel(
    const ushort_t* __restrict__ zh, const ushort_t* __restrict__ zl,
    const ushort_t* __restrict__ wkh, const ushort_t* __restrict__ wkl,
    const float* __restrict__ bk, ushort_t* __restrict__ P, int n) {
  int w = threadIdx.x >> 6, l = threadIdx.x & 63;
  int n0 = blockIdx.x * 64 + w * 16;
  int arow = n0 + (l & 15);
  if (arow >= n) arow = n - 1;
  int koff = (l >> 4) * 8;
  bf16x8 ah[4], al[4];
#pragma unroll
  for (int kk = 0; kk < 4; ++kk) {
    size_t zo = (size_t)arow * D + kk * 32 + koff;
    ah[kk] = *(const bf16x8*)(zh + zo);
    al[kk] = *(const bf16x8*)(zl + zo);
  }
  int col16 = l & 15, rgrp = (l >> 4) * 4;
  for (int t = 0; t < NTYPES; ++t) {
    const ushort_t* bh0 = wkh + (size_t)t * (D * D);
    const ushort_t* bl0 = wkl + (size_t)t * (D * D);
    ushort_t* Pt = P + (size_t)t * n * D;
#pragma unroll
    for (int cp = 0; cp < 4; ++cp) {
      bf16x8 Bh[2][4], Bl[2][4];
#pragma unroll
      for (int cc = 0; cc < 2; ++cc)
#pragma unroll
        for (int kk = 0; kk < 4; ++kk) {
          size_t o = ((size_t)((cp * 2 + cc) * 4 + kk) * 64 + l) * 8;
          Bh[cc][kk] = *(const bf16x8*)(bh0 + o);
          Bl[cc][kk] = *(const bf16x8*)(bl0 + o);
        }
      f32x4 aa[2], ab[2], ac[2];
#pragma unroll
      for (int cc = 0; cc < 2; ++cc) {
        float bias = bk[t * D + (cp * 2 + cc) * 16 + col16];
        aa[cc] = (f32x4){bias, bias, bias, bias};
        ab[cc] = (f32x4){0.f, 0.f, 0.f, 0.f};
        ac[cc] = (f32x4){0.f, 0.f, 0.f, 0.f};
      }
#pragma unroll
      for (int kk = 0; kk < 4; ++kk)
#pragma unroll
        for (int cc = 0; cc < 2; ++cc) {
          aa[cc] = __builtin_amdgcn_mfma_f32_16x16x32_bf16(ah[kk], Bh[cc][kk], aa[cc], 0, 0, 0);
          ab[cc] = __builtin_amdgcn_mfma_f32_16x16x32_bf16(ah[kk], Bl[cc][kk], ab[cc], 0, 0, 0);
          ac[cc] = __builtin_amdgcn_mfma_f32_16x16x32_bf16(al[kk], Bh[cc][kk], ac[cc], 0, 0, 0);
        }
#pragma unroll
      for (int cc = 0; cc < 2; ++cc)
#pragma unroll
        for (int r = 0; r < 4; ++r) {
          int row = n0 + rgrp + r;
          if (row < n)
            Pt[(size_t)row * D + (cp * 2 + cc) * 16 + col16] =
                bfbits(aa[cc][r] + ab[cc][r] + ac[cc][r]);
        }
    }
  }
}

// ---------------------------------------------------------------------------
// K3: CSR build by src — hist + hierarchical 3-pass scan + fill
// ---------------------------------------------------------------------------
__global__ void zero_kernel(int* __restrict__ p, int n) {
  int i = blockIdx.x * 256 + threadIdx.x;
  if (i < n) p[i] = 0;
}

__global__ void hist_kernel(const int* __restrict__ edges,
                            int* __restrict__ cnt, int E) {
  int e = blockIdx.x * 256 + threadIdx.x;
  if (e >= E) return;
  atomicAdd(&cnt[edges[e]], 1);
}

__global__ __launch_bounds__(256) void scanA_kernel(const int* __restrict__ cnt,
                                                    int* __restrict__ loc,
                                                    int* __restrict__ bsums, int n) {
  __shared__ int ts[256];
  int tid = threadIdx.x;
  int base = blockIdx.x * 1024 + tid * 4;
  int v0 = (base + 0 < n) ? cnt[base + 0] : 0;
  int v1 = (base + 1 < n) ? cnt[base + 1] : 0;
  int v2 = (base + 2 < n) ? cnt[base + 2] : 0;
  int v3 = (base + 3 < n) ? cnt[base + 3] : 0;
  int s = v0 + v1 + v2 + v3;
  ts[tid] = s;
  __syncthreads();
  for (int o = 1; o < 256; o <<= 1) {
    int t = (tid >= o) ? ts[tid - o] : 0;
    __syncthreads();
    ts[tid] += t;
    __syncthreads();
  }
  int run = ts[tid] - s;
  if (base + 0 < n) loc[base + 0] = run;  run += v0;
  if (base + 1 < n) loc[base + 1] = run;  run += v1;
  if (base + 2 < n) loc[base + 2] = run;  run += v2;
  if (base + 3 < n) loc[base + 3] = run;
  if (tid == 255) bsums[blockIdx.x] = ts[255];
}

__global__ __launch_bounds__(256) void scanB_kernel(int* __restrict__ bsums, int nb,
                                                    int* __restrict__ total) {
  __shared__ int ts[256];
  int tid = threadIdx.x;
  int per = (nb + 255) / 256;
  int start = tid * per;
  int end = min(start + per, nb);
  int s = 0;
  for (int i = start; i < end; ++i) s += bsums[i];
  ts[tid] = s;
  __syncthreads();
  for (int o = 1; o < 256; o <<= 1) {
    int t = (tid >= o) ? ts[tid - o] : 0;
    __syncthreads();
    ts[tid] += t;
    __syncthreads();
  }
  int run = ts[tid] - s;
  for (int i = start; i < end; ++i) {
    int v = bsums[i];
    bsums[i] = run;
    run += v;
  }
  if (tid == 255) *total = ts[255];
}

__global__ void scanC_kernel(const int* __restrict__ loc,
                             const int* __restrict__ bsums,
                             const int* __restrict__ total,
                             int* __restrict__ offs, int* __restrict__ cursor,
                             int n) {
  int i = blockIdx.x * 256 + threadIdx.x;
  if (i < n) {
    int o = loc[i] + bsums[i >> 10];
    offs[i] = o;
    cursor[i] = o;
  }
  if (i == 0) offs[n] = *total;
}

__global__ void fill_kernel(const int* __restrict__ edges,
                            const unsigned char* __restrict__ masks,
                            const int* __restrict__ flag,
                            int* __restrict__ cursor,
                            uint_t* __restrict__ elist, int E) {
  int e = blockIdx.x * 256 + threadIdx.x;
  if (e >= E) return;
  int is8 = *flag;
  int t = decode_etype(masks, E, e, is8);
  int dst = edges[E + e];
  int pos = atomicAdd(&cursor[edges[e]], 1);
  elist[pos] = ((uint_t)t << 29) | (uint_t)(dst & 0x1FFFFFFF);
}

// ---------------------------------------------------------------------------
// K4: per-node attention. 16 lanes per node (8 dims/lane), 4 nodes/wave.
// Double-buffered 4-edge chunks (8 gathers in flight), batched online softmax,
// OOB edges encoded as p=-1e30 with zeroed k (no divergence in compute).
// ---------------------------------------------------------------------------
#define LOAD_CHUNK(PV, KV, J0)                                               \
  {                                                                          \
    _Pragma("unroll")                                                        \
    for (int i_ = 0; i_ < 4; ++i_) {                                         \
      int j_ = (J0) + i_;                                                    \
      if (j_ < end) {                                                        \
        uint_t e_ = elist[j_];                                               \
        PV[i_] = e_;                                                         \
        KV[i_] = *(const bf16x8*)(P + ((size_t)(e_ >> 29) * n +              \
                                       (e_ & 0x1FFFFFFFu)) * D + gl * 8);    \
      } else {                                                               \
        PV[i_] = 0u;                                                         \
        KV[i_] = KZ;                                                         \
      }                                                                      \
    }                                                                        \
  }

#define COMPUTE_CHUNK(PV, KV, J0)                                            \
  {                                                                          \
    float p_[4];                                                             \
    _Pragma("unroll")                                                        \
    for (int i_ = 0; i_ < 4; ++i_) {                                         \
      int t_ = PV[i_] >> 29;                                                 \
      bf16x8 q_ = (t_ == 0) ? qv0 : (t_ == 1) ? qv1 : (t_ == 2) ? qv2        \
                  : (t_ == 3) ? qv3 : qv4;                                   \
      float s_ = 0.f;                                                        \
      _Pragma("unroll")                                                      \
      for (int d_ = 0; d_ < 8; ++d_)                                         \
        s_ += (float)q_[d_] * (float)KV[i_][d_];                             \
      s_ += __shfl_xor(s_, 1);                                               \
      p_[i_] = ((J0) + i_ < end) ? s_ : -1e30f;                              \
    }                                                                        \
    float nm_ = fmaxf(fmaxf(m, p_[0]), fmaxf(p_[1], p_[2]));                 \
    nm_ = fmaxf(nm_, p_[3]);                                                 \
    float sc_ = __expf(m - nm_);                                             \
    float w0_ = __expf(p_[0] - nm_), w1_ = __expf(p_[1] - nm_);              \
    float w2_ = __expf(p_[2] - nm_), w3_ = __expf(p_[3] - nm_);              \
    den = den * sc_ + w0_ + w1_ + w2_ + w3_;                                 \
    _Pragma("unroll")                                                        \
    for (int d_ = 0; d_ < 8; ++d_)                                           \
      a[d_] = a[d_] * sc_ + w0_ * (float)KV[0][d_] + w1_ * (float)KV[1][d_]  \
              + w2_ * (float)KV[2][d_] + w3_ * (float)KV[3][d_];             \
    m = nm_;                                                                 \
  }

__global__ __launch_bounds__(256, 3) void attn_kernel(
    const float* __restrict__ x, const ushort_t* __restrict__ P,
    const int* __restrict__ offs, const uint_t* __restrict__ elist,
    float* __restrict__ out, int n) {
  int node = (blockIdx.x * 256 + threadIdx.x) >> 4;
  int gl = threadIdx.x & 15;
  if (node >= n) return;

  bf16x8 qv0 = *(const bf16x8*)(P + ((size_t)0 * n + node) * D + gl * 8);
  bf16x8 qv1 = *(const bf16x8*)(P + ((size_t)1 * n + node) * D + gl * 8);
  bf16x8 qv2 = *(const bf16x8*)(P + ((size_t)2 * n + node) * D + gl * 8);
  bf16x8 qv3 = *(const bf16x8*)(P + ((size_t)3 * n + node) * D + gl * 8);
  bf16x8 qv4 = *(const bf16x8*)(P + ((size_t)4 * n + node) * D + gl * 8);

  const bf16x8 KZ = {};
  float m = -1e30f, den = 0.f;
  float a[8];
#pragma unroll
  for (int i = 0; i < 8; ++i) a[i] = 0.f;

  int beg = offs[node], end = offs[node + 1];

  uint_t pvA[4], pvB[4];
  bf16x8 kvA[4], kvB[4];
  LOAD_CHUNK(pvA, kvA, beg)
  for (int j0 = beg; j0 < end; j0 += 8) {
    LOAD_CHUNK(pvB, kvB, j0 + 4)
    COMPUTE_CHUNK(pvA, kvA, j0)
    LOAD_CHUNK(pvA, kvA, j0 + 8)
    COMPUTE_CHUNK(pvB, kvB, j0 + 4)
  }

  float inv = (end > beg) ? 1.f / den : 0.f;
  const float* xr = x + (size_t)node * D + gl * 8;
  float* orow = out + (size_t)node * D + gl * 8;
  float4 xa = *(const float4*)xr;
  float4 xb = *(const float4*)(xr + 4);
  float4 oa, ob;
  oa.x = xa.x + a[0] * inv; oa.y = xa.y + a[1] * inv;
  oa.z = xa.z + a[2] * inv; oa.w = xa.w + a[3] * inv;
  ob.x = xb.x + a[4] * inv; ob.y = xb.y + a[5] * inv;
  ob.z = xb.z + a[6] * inv; ob.w = xb.w + a[7] * inv;
  *(float4*)orow = oa;
  *(float4*)(orow + 4) = ob;
}

// ---------------------------------------------------------------------------
// K5: fused LN2 + FFN + residual via MFMA, in-place on out (holds x2).
// Now 3 blocks/CU (LDS 42KB x 3 = 126KB fits; VGPR cap 170).
// ---------------------------------------------------------------------------
__global__ __launch_bounds__(256, 3) void ffn_mfma_kernel(
    const ushort_t* __restrict__ w1h, const ushort_t* __restrict__ w1l,
    const ushort_t* __restrict__ w2h, const ushort_t* __restrict__ w2l,
    const float* __restrict__ b1, const float* __restrict__ b2,
    const float* __restrict__ g, const float* __restrict__ bln,
    float* __restrict__ out, int n) {
  __shared__ ushort_t z2h[64 * D];
  __shared__ ushort_t z2l[64 * D];
  __shared__ float hmb[4][16 * 36];
  int tid = threadIdx.x, w = tid >> 6, l = tid & 63;
  int n0 = blockIdx.x * 64;

  for (int i = w; i < 64; i += 4) {
    int r = n0 + i;
    float v0 = 0.f, v1 = 0.f;
    if (r < n) {
      v0 = out[(size_t)r * D + l];
      v1 = out[(size_t)r * D + 64 + l];
    }
    float s = v0 + v1, ss = v0 * v0 + v1 * v1;
    for (int o = 32; o; o >>= 1) { s += __shfl_xor(s, o); ss += __shfl_xor(ss, o); }
    float mu = s * (1.f / D);
    float var = ss * (1.f / D) - mu * mu;
    float rs = rsqrtf(var + LN_EPS);
    float z0 = (v0 - mu) * rs * g[l] + bln[l];
    float z1 = (v1 - mu) * rs * g[l + 64] + bln[l + 64];
    int sw = (i & 7) << 3;
    int e0 = (i * D + l) ^ sw;
    int e1 = (i * D + l + 64) ^ sw;
    __bf16 h0 = (__bf16)z0, h1 = (__bf16)z1;
    z2h[e0] = __builtin_bit_cast(ushort_t, h0);
    z2h[e1] = __builtin_bit_cast(ushort_t, h1);
    __bf16 l0 = (__bf16)(z0 - (float)h0), l1 = (__bf16)(z1 - (float)h1);
    z2l[e0] = __builtin_bit_cast(ushort_t, l0);
    z2l[e1] = __builtin_bit_cast(ushort_t, l1);
  }
  __syncthreads();

  int lrow = w * 16 + (l & 15);
  int koff = (l >> 4) * 8;
  bf16x8 ah[4], al[4];
#pragma unroll
  for (int kk = 0; kk < 4; ++kk) {
    int e = (lrow * D + kk * 32 + koff) ^ ((lrow & 7) << 3);
    ah[kk] = *(const bf16x8*)(z2h + e);
    al[kk] = *(const bf16x8*)(z2l + e);
  }

  int col16 = l & 15, rgrp = (l >> 4) * 4;
  f32x4 acc2[8];
#pragma unroll
  for (int c = 0; c < 8; ++c) acc2[c] = (f32x4){0.f, 0.f, 0.f, 0.f};
  float* hbp = &hmb[w][0];

  for (int kk2 = 0; kk2 < 16; ++kk2) {
    bf16x8 B1h[2][4], B1l[2][4];
#pragma unroll
    for (int cc = 0; cc < 2; ++cc)
#pragma unroll
      for (int kk = 0; kk < 4; ++kk) {
        size_t o = ((size_t)((kk2 * 2 + cc) * 4 + kk) * 64 + l) * 8;
        B1h[cc][kk] = *(const bf16x8*)(w1h + o);
        B1l[cc][kk] = *(const bf16x8*)(w1l + o);
      }
    f32x4 ha[2], hb[2], hc[2];
#pragma unroll
    for (int cc = 0; cc < 2; ++cc) {
      float bias = b1[(kk2 * 2 + cc) * 16 + col16];
      ha[cc] = (f32x4){bias, bias, bias, bias};
      hb[cc] = (f32x4){0.f, 0.f, 0.f, 0.f};
      hc[cc] = (f32x4){0.f, 0.f, 0.f, 0.f};
    }
#pragma unroll
    for (int kk = 0; kk < 4; ++kk)
#pragma unroll
      for (int cc = 0; cc < 2; ++cc) {
        ha[cc] = __builtin_amdgcn_mfma_f32_16x16x32_bf16(ah[kk], B1h[cc][kk], ha[cc], 0, 0, 0);
        hb[cc] = __builtin_amdgcn_mfma_f32_16x16x32_bf16(ah[kk], B1l[cc][kk], hb[cc], 0, 0, 0);
        hc[cc] = __builtin_amdgcn_mfma_f32_16x16x32_bf16(al[kk], B1h[cc][kk], hc[cc], 0, 0, 0);
      }
#pragma unroll
    for (int cc = 0; cc < 2; ++cc)
#pragma unroll
      for (int r = 0; r < 4; ++r)
        hbp[(rgrp + r) * 36 + cc * 16 + col16] =
            fmaxf(ha[cc][r] + hb[cc][r] + hc[cc][r], 0.f);
    float av[8];
    *(float4*)&av[0] = *(const float4*)&hbp[(l & 15) * 36 + koff];
    *(float4*)&av[4] = *(const float4*)&hbp[(l & 15) * 36 + koff + 4];
    bf16x8 a2h, a2l;
#pragma unroll
    for (int j = 0; j < 8; ++j) {
      __bf16 hv = (__bf16)av[j];
      a2h[j] = hv;
      a2l[j] = (__bf16)(av[j] - (float)hv);
    }
    bf16x8 B2h[8], B2l[8];
#pragma unroll
    for (int c2 = 0; c2 < 8; ++c2) {
      size_t o = ((size_t)(c2 * 16 + kk2) * 64 + l) * 8;
      B2h[c2] = *(const bf16x8*)(w2h + o);
      B2l[c2] = *(const bf16x8*)(w2l + o);
    }
#pragma unroll
    for (int c2 = 0; c2 < 8; ++c2) {
      acc2[c2] = __builtin_amdgcn_mfma_f32_16x16x32_bf16(a2h, B2h[c2], acc2[c2], 0, 0, 0);
      acc2[c2] = __builtin_amdgcn_mfma_f32_16x16x32_bf16(a2h, B2l[c2], acc2[c2], 0, 0, 0);
      acc2[c2] = __builtin_amdgcn_mfma_f32_16x16x32_bf16(a2l, B2h[c2], acc2[c2], 0, 0, 0);
    }
  }

#pragma unroll
  for (int c2 = 0; c2 < 8; ++c2) {
    float bias2 = b2[c2 * 16 + col16];
#pragma unroll
    for (int r = 0; r < 4; ++r) {
      int row = n0 + w * 16 + rgrp + r;
      if (row < n) {
        size_t o = (size_t)row * D + c2 * 16 + col16;
        out[o] = out[o] + acc2[c2][r] + bias2;
      }
    }
  }
}

// ---------------------------------------------------------------------------
extern "C" void kernel_launch(void* const* d_in, const int* in_sizes, int n_in,
                              void* d_out, int out_size, void* d_ws, size_t ws_size,
                              hipStream_t stream) {
  const float* x      = (const float*)d_in[0];
  const int* edges    = (const int*)d_in[1];
  const unsigned char* masks = (const unsigned char*)d_in[2];
  const float* Wk     = (const float*)d_in[3];
  const float* bk     = (const float*)d_in[4];
  const float* ln1_g  = (const float*)d_in[5];
  const float* ln1_b  = (const float*)d_in[6];
  const float* ln2_g  = (const float*)d_in[7];
  const float* ln2_b  = (const float*)d_in[8];
  const float* W1     = (const float*)d_in[9];
  const float* b1     = (const float*)d_in[10];
  const float* W2     = (const float*)d_in[11];
  const float* b2     = (const float*)d_in[12];
  float* out = (float*)d_out;

  const int n = in_sizes[0] / D;
  const int E = in_sizes[1] / 2;
  const int nb = (n + 1023) / 1024;

  // workspace layout (~69 MB)
  char* ws = (char*)d_ws;
  size_t off = 0;
  ushort_t* P = (ushort_t*)(ws + off);  off += (size_t)NTYPES * n * D * sizeof(ushort_t);
  int* cnt    = (int*)(ws + off);       off += (size_t)n * sizeof(int);
  int* offs   = (int*)(ws + off);       off += (size_t)(n + 1) * sizeof(int);
  int* cursor = (int*)(ws + off);       off += (size_t)n * sizeof(int);
  int* loc    = (int*)(ws + off);       off += (size_t)n * sizeof(int);
  int* bsums  = (int*)(ws + off);       off += (size_t)nb * sizeof(int);
  int* total  = (int*)(ws + off);       off += 64;
  uint_t* elist = (uint_t*)(ws + off);  off += (size_t)E * sizeof(uint_t);
  int* flag   = (int*)(ws + off);       off += 64;
  ushort_t* wkh = (ushort_t*)(ws + off); off += (size_t)NTYPES * D * D * sizeof(ushort_t);
  ushort_t* wkl = (ushort_t*)(ws + off); off += (size_t)NTYPES * D * D * sizeof(ushort_t);
  ushort_t* w1h = (ushort_t*)(ws + off); off += (size_t)D * FFDIM * sizeof(ushort_t);
  ushort_t* w1l = (ushort_t*)(ws + off); off += (size_t)D * FFDIM * sizeof(ushort_t);
  ushort_t* w2h = (ushort_t*)(ws + off); off += (size_t)FFDIM * D * sizeof(ushort_t);
  ushort_t* w2l = (ushort_t*)(ws + off); off += (size_t)FFDIM * D * sizeof(ushort_t);
  (void)ws_size; (void)n_in; (void)out_size;

  // z hi/lo parked in d_out (dead before attn writes x2 there)
  ushort_t* zh = (ushort_t*)out;
  ushort_t* zl = zh + (size_t)n * D;

  // K0: mask dtype detection
  detect_kernel<<<1, 64, 0, stream>>>(masks, E, flag);

  // K1: LN1 -> z hi/lo
  ln1_kernel<<<(n + 3) / 4, 256, 0, stream>>>(x, ln1_g, ln1_b, zh, zl, n);

  // K1b: weight fragment conversion
  {
    dim3 gwk((8 * 4 * 64 + 255) / 256, NTYPES);
    conv_frag_kernel<<<gwk, 256, 0, stream>>>(Wk, wkh, wkl, D, D,
                                              (size_t)D * D, (size_t)D * D);
    dim3 gw1(((FFDIM / 16) * 4 * 64 + 255) / 256, 1);
    conv_frag_kernel<<<gw1, 256, 0, stream>>>(W1, w1h, w1l, D, FFDIM, 0, 0);
    dim3 gw2((8 * (FFDIM / 32) * 64 + 255) / 256, 1);
    conv_frag_kernel<<<gw2, 256, 0, stream>>>(W2, w2h, w2l, FFDIM, D, 0, 0);
  }

  // K2: projections
  proj_mfma_kernel<<<(n + 63) / 64, 256, 0, stream>>>(zh, zl, wkh, wkl, bk, P, n);

  // K3: CSR build by src (hierarchical scan)
  zero_kernel<<<(n + 255) / 256, 256, 0, stream>>>(cnt, n);
  hist_kernel<<<(E + 255) / 256, 256, 0, stream>>>(edges, cnt, E);
  scanA_kernel<<<nb, 256, 0, stream>>>(cnt, loc, bsums, n);
  scanB_kernel<<<1, 256, 0, stream>>>(bsums, nb, total);
  scanC_kernel<<<(n + 255) / 256, 256, 0, stream>>>(loc, bsums, total, offs, cursor, n);
  fill_kernel<<<(E + 255) / 256, 256, 0, stream>>>(edges, masks, flag, cursor, elist, E);

  // K4: attention -> out = x + attn
  attn_kernel<<<(n + 15) / 16, 256, 0, stream>>>(x, P, offs, elist, out, n);

  // K5: LN2 + FFN + residual
  ffn_mfma_kernel<<<(n + 63) / 64, 256, 0, stream>>>(w1h, w1l, w2h, w2l,
                                                     b1, b2, ln2_g, ln2_b, out, n);
}

// Round 7
// 297.774 us; speedup vs baseline: 1.1297x; 1.1297x over previous
//
#include <hip/hip_runtime.h>

// Problem constants (match reference)
#define D 128
#define H 8
#define DK 16
#define FFDIM 512
#define NTYPES 5
#define LN_EPS 1e-5f

typedef __bf16 bf16x8 __attribute__((ext_vector_type(8)));
typedef float f32x4 __attribute__((ext_vector_type(4)));
typedef unsigned short ushort_t;
typedef unsigned int uint_t;

__device__ inline ushort_t bfbits(float f) {
  __bf16 b = (__bf16)f;
  return __builtin_bit_cast(ushort_t, b);
}
__device__ inline float bf2f(ushort_t u) {
  return __uint_as_float(((uint_t)u) << 16);
}

// ---------------------------------------------------------------------------
// K0: detect mask dtype (byte-bool vs int32). flag=1 for byte masks.
// ---------------------------------------------------------------------------
__global__ void detect_kernel(const unsigned char* __restrict__ m8, int E,
                              int* __restrict__ flag) {
  int lane = threadIdx.x;  // 64 threads, 1 wave
  int s = 1;
  if (lane < E) {
    s = 0;
#pragma unroll
    for (int i = 0; i < NTYPES; ++i) s += (m8[(size_t)i * E + lane] != 0);
  }
  unsigned long long b = __ballot(s == 1);
  if (lane == 0) *flag = (b == ~0ull) ? 1 : 0;
}

__device__ inline int decode_etype(const unsigned char* __restrict__ m8,
                                   int E, int e, int is8) {
  int t = 0;
  if (is8) {
#pragma unroll
    for (int i = 1; i < NTYPES; ++i) t += i * (m8[(size_t)i * E + e] != 0);
  } else {
    const int* m32 = (const int*)m8;
#pragma unroll
    for (int i = 1; i < NTYPES; ++i) t += i * (m32[(size_t)i * E + e] != 0);
  }
  return t > (NTYPES - 1) ? (NTYPES - 1) : t;
}

// ---------------------------------------------------------------------------
// K1: LayerNorm x -> z, stored as hi/lo bf16 split (parked in d_out)
// ---------------------------------------------------------------------------
__global__ __launch_bounds__(256) void ln1_kernel(
    const float* __restrict__ x, const float* __restrict__ g,
    const float* __restrict__ b, ushort_t* __restrict__ zh,
    ushort_t* __restrict__ zl, int n) {
  int row = blockIdx.x * 4 + (threadIdx.x >> 6);
  int lane = threadIdx.x & 63;
  if (row >= n) return;
  const float* xr = x + (size_t)row * D;
  float v0 = xr[lane], v1 = xr[lane + 64];
  float s = v0 + v1, ss = v0 * v0 + v1 * v1;
  for (int o = 32; o; o >>= 1) { s += __shfl_xor(s, o); ss += __shfl_xor(ss, o); }
  float mu = s * (1.f / D);
  float var = ss * (1.f / D) - mu * mu;
  float rs = rsqrtf(var + LN_EPS);
  float z0 = (v0 - mu) * rs * g[lane] + b[lane];
  float z1 = (v1 - mu) * rs * g[lane + 64] + b[lane + 64];
  size_t o0 = (size_t)row * D + lane, o1 = o0 + 64;
  __bf16 h0 = (__bf16)z0, h1 = (__bf16)z1;
  zh[o0] = __builtin_bit_cast(ushort_t, h0);
  zh[o1] = __builtin_bit_cast(ushort_t, h1);
  __bf16 l0 = (__bf16)(z0 - (float)h0), l1 = (__bf16)(z1 - (float)h1);
  zl[o0] = __builtin_bit_cast(ushort_t, l0);
  zl[o1] = __builtin_bit_cast(ushort_t, l1);
}

// ---------------------------------------------------------------------------
// K1b: convert a row-major f32 weight [K][N] into MFMA B-fragment order,
// bf16 hi only (weight-lo term is below the bf16-storage noise floor).
// frag[((c*(K/32)+kk)*64 + lane)*8 + j] = W[kk*32 + (lane>>4)*8 + j][c*16 + (lane&15)]
// ---------------------------------------------------------------------------
__global__ void conv_frag_kernel(const float* __restrict__ W,
                                 ushort_t* __restrict__ hi,
                                 int K, int Ncol, size_t matW, size_t matF) {
  int gid = blockIdx.x * 256 + threadIdx.x;
  int total = (Ncol / 16) * (K / 32) * 64;
  if (gid >= total) return;
  const float* Wm = W + (size_t)blockIdx.y * matW;
  ushort_t* him = hi + (size_t)blockIdx.y * matF;
  int l = gid & 63;
  int ck = gid >> 6;
  int kk = ck % (K / 32);
  int c = ck / (K / 32);
  int row0 = kk * 32 + (l >> 4) * 8;
  int col = c * 16 + (l & 15);
  size_t ob = (size_t)gid * 8;
#pragma unroll
  for (int j = 0; j < 8; ++j) {
    float w = Wm[(size_t)(row0 + j) * Ncol + col];
    __bf16 h = (__bf16)w;
    him[ob + j] = __builtin_bit_cast(ushort_t, h);
  }
}

// ---------------------------------------------------------------------------
// K2: proj via MFMA: P[t][node][d] = bf16( (zh+zl) @ Wkh[t] + bk[t] )
// 2-term: ah*Bh + al*Bh. Weight-hi only => half the loads, 2/3 the MFMA.
// ---------------------------------------------------------------------------
__global__ __launch_bounds__(256, 3) void proj_mfma_kernel(
    const ushort_t* __restrict__ zh, const ushort_t* __restrict__ zl,
    const ushort_t* __restrict__ wkh,
    const float* __restrict__ bk, ushort_t* __restrict__ P, int n) {
  int w = threadIdx.x >> 6, l = threadIdx.x & 63;
  int n0 = blockIdx.x * 64 + w * 16;
  int arow = n0 + (l & 15);
  if (arow >= n) arow = n - 1;
  int koff = (l >> 4) * 8;
  bf16x8 ah[4], al[4];
#pragma unroll
  for (int kk = 0; kk < 4; ++kk) {
    size_t zo = (size_t)arow * D + kk * 32 + koff;
    ah[kk] = *(const bf16x8*)(zh + zo);
    al[kk] = *(const bf16x8*)(zl + zo);
  }
  int col16 = l & 15, rgrp = (l >> 4) * 4;
  for (int t = 0; t < NTYPES; ++t) {
    const ushort_t* bh0 = wkh + (size_t)t * (D * D);
    ushort_t* Pt = P + (size_t)t * n * D;
#pragma unroll
    for (int cp = 0; cp < 4; ++cp) {
      // batched B loads for the 2 c-tiles of this pair (8 x dwordx4)
      bf16x8 Bh[2][4];
#pragma unroll
      for (int cc = 0; cc < 2; ++cc)
#pragma unroll
        for (int kk = 0; kk < 4; ++kk) {
          size_t o = ((size_t)((cp * 2 + cc) * 4 + kk) * 64 + l) * 8;
          Bh[cc][kk] = *(const bf16x8*)(bh0 + o);
        }
      // 4 independent accumulator chains of length 4
      f32x4 aa[2], ac[2];
#pragma unroll
      for (int cc = 0; cc < 2; ++cc) {
        float bias = bk[t * D + (cp * 2 + cc) * 16 + col16];
        aa[cc] = (f32x4){bias, bias, bias, bias};
        ac[cc] = (f32x4){0.f, 0.f, 0.f, 0.f};
      }
#pragma unroll
      for (int kk = 0; kk < 4; ++kk)
#pragma unroll
        for (int cc = 0; cc < 2; ++cc) {
          aa[cc] = __builtin_amdgcn_mfma_f32_16x16x32_bf16(ah[kk], Bh[cc][kk], aa[cc], 0, 0, 0);
          ac[cc] = __builtin_amdgcn_mfma_f32_16x16x32_bf16(al[kk], Bh[cc][kk], ac[cc], 0, 0, 0);
        }
#pragma unroll
      for (int cc = 0; cc < 2; ++cc)
#pragma unroll
        for (int r = 0; r < 4; ++r) {
          int row = n0 + rgrp + r;
          if (row < n)
            Pt[(size_t)row * D + (cp * 2 + cc) * 16 + col16] =
                bfbits(aa[cc][r] + ac[cc][r]);
        }
    }
  }
}

// ---------------------------------------------------------------------------
// K3: CSR build by src — hist + hierarchical 3-pass scan + fill
// ---------------------------------------------------------------------------
__global__ void zero_kernel(int* __restrict__ p, int n) {
  int i = blockIdx.x * 256 + threadIdx.x;
  if (i < n) p[i] = 0;
}

__global__ void hist_kernel(const int* __restrict__ edges,
                            int* __restrict__ cnt, int E) {
  int e = blockIdx.x * 256 + threadIdx.x;
  if (e >= E) return;
  atomicAdd(&cnt[edges[e]], 1);
}

__global__ __launch_bounds__(256) void scanA_kernel(const int* __restrict__ cnt,
                                                    int* __restrict__ loc,
                                                    int* __restrict__ bsums, int n) {
  __shared__ int ts[256];
  int tid = threadIdx.x;
  int base = blockIdx.x * 1024 + tid * 4;
  int v0 = (base + 0 < n) ? cnt[base + 0] : 0;
  int v1 = (base + 1 < n) ? cnt[base + 1] : 0;
  int v2 = (base + 2 < n) ? cnt[base + 2] : 0;
  int v3 = (base + 3 < n) ? cnt[base + 3] : 0;
  int s = v0 + v1 + v2 + v3;
  ts[tid] = s;
  __syncthreads();
  for (int o = 1; o < 256; o <<= 1) {
    int t = (tid >= o) ? ts[tid - o] : 0;
    __syncthreads();
    ts[tid] += t;
    __syncthreads();
  }
  int run = ts[tid] - s;
  if (base + 0 < n) loc[base + 0] = run;  run += v0;
  if (base + 1 < n) loc[base + 1] = run;  run += v1;
  if (base + 2 < n) loc[base + 2] = run;  run += v2;
  if (base + 3 < n) loc[base + 3] = run;
  if (tid == 255) bsums[blockIdx.x] = ts[255];
}

__global__ __launch_bounds__(256) void scanB_kernel(int* __restrict__ bsums, int nb,
                                                    int* __restrict__ total) {
  __shared__ int ts[256];
  int tid = threadIdx.x;
  int per = (nb + 255) / 256;
  int start = tid * per;
  int end = min(start + per, nb);
  int s = 0;
  for (int i = start; i < end; ++i) s += bsums[i];
  ts[tid] = s;
  __syncthreads();
  for (int o = 1; o < 256; o <<= 1) {
    int t = (tid >= o) ? ts[tid - o] : 0;
    __syncthreads();
    ts[tid] += t;
    __syncthreads();
  }
  int run = ts[tid] - s;
  for (int i = start; i < end; ++i) {
    int v = bsums[i];
    bsums[i] = run;
    run += v;
  }
  if (tid == 255) *total = ts[255];
}

__global__ void scanC_kernel(const int* __restrict__ loc,
                             const int* __restrict__ bsums,
                             const int* __restrict__ total,
                             int* __restrict__ offs, int* __restrict__ cursor,
                             int n) {
  int i = blockIdx.x * 256 + threadIdx.x;
  if (i < n) {
    int o = loc[i] + bsums[i >> 10];
    offs[i] = o;
    cursor[i] = o;
  }
  if (i == 0) offs[n] = *total;
}

__global__ void fill_kernel(const int* __restrict__ edges,
                            const unsigned char* __restrict__ masks,
                            const int* __restrict__ flag,
                            int* __restrict__ cursor,
                            uint_t* __restrict__ elist, int E) {
  int e = blockIdx.x * 256 + threadIdx.x;
  if (e >= E) return;
  int is8 = *flag;
  int t = decode_etype(masks, E, e, is8);
  int dst = edges[E + e];
  int pos = atomicAdd(&cursor[edges[e]], 1);
  elist[pos] = ((uint_t)t << 29) | (uint_t)(dst & 0x1FFFFFFF);
}

// ---------------------------------------------------------------------------
// K4: per-node attention. 16 lanes per node (8 dims/lane), 4 nodes/wave.
// Double-buffered 4-edge chunks, batched online softmax.
// ---------------------------------------------------------------------------
#define LOAD_CHUNK(PV, KV, J0)                                               \
  {                                                                          \
    _Pragma("unroll")                                                        \
    for (int i_ = 0; i_ < 4; ++i_) {                                         \
      int j_ = (J0) + i_;                                                    \
      if (j_ < end) {                                                        \
        uint_t e_ = elist[j_];                                               \
        PV[i_] = e_;                                                         \
        KV[i_] = *(const bf16x8*)(P + ((size_t)(e_ >> 29) * n +              \
                                       (e_ & 0x1FFFFFFFu)) * D + gl * 8);    \
      } else {                                                               \
        PV[i_] = 0u;                                                         \
        KV[i_] = KZ;                                                         \
      }                                                                      \
    }                                                                        \
  }

#define COMPUTE_CHUNK(PV, KV, J0)                                            \
  {                                                                          \
    float p_[4];                                                             \
    _Pragma("unroll")                                                        \
    for (int i_ = 0; i_ < 4; ++i_) {                                         \
      int t_ = PV[i_] >> 29;                                                 \
      bf16x8 q_ = (t_ == 0) ? qv0 : (t_ == 1) ? qv1 : (t_ == 2) ? qv2        \
                  : (t_ == 3) ? qv3 : qv4;                                   \
      float s_ = 0.f;                                                        \
      _Pragma("unroll")                                                      \
      for (int d_ = 0; d_ < 8; ++d_)                                         \
        s_ += (float)q_[d_] * (float)KV[i_][d_];                             \
      s_ += __shfl_xor(s_, 1);                                               \
      p_[i_] = ((J0) + i_ < end) ? s_ : -1e30f;                              \
    }                                                                        \
    float nm_ = fmaxf(fmaxf(m, p_[0]), fmaxf(p_[1], p_[2]));                 \
    nm_ = fmaxf(nm_, p_[3]);                                                 \
    float sc_ = __expf(m - nm_);                                             \
    float w0_ = __expf(p_[0] - nm_), w1_ = __expf(p_[1] - nm_);              \
    float w2_ = __expf(p_[2] - nm_), w3_ = __expf(p_[3] - nm_);              \
    den = den * sc_ + w0_ + w1_ + w2_ + w3_;                                 \
    _Pragma("unroll")                                                        \
    for (int d_ = 0; d_ < 8; ++d_)                                           \
      a[d_] = a[d_] * sc_ + w0_ * (float)KV[0][d_] + w1_ * (float)KV[1][d_]  \
              + w2_ * (float)KV[2][d_] + w3_ * (float)KV[3][d_];             \
    m = nm_;                                                                 \
  }

__global__ __launch_bounds__(256, 3) void attn_kernel(
    const float* __restrict__ x, const ushort_t* __restrict__ P,
    const int* __restrict__ offs, const uint_t* __restrict__ elist,
    float* __restrict__ out, int n) {
  int node = (blockIdx.x * 256 + threadIdx.x) >> 4;
  int gl = threadIdx.x & 15;
  if (node >= n) return;

  bf16x8 qv0 = *(const bf16x8*)(P + ((size_t)0 * n + node) * D + gl * 8);
  bf16x8 qv1 = *(const bf16x8*)(P + ((size_t)1 * n + node) * D + gl * 8);
  bf16x8 qv2 = *(const bf16x8*)(P + ((size_t)2 * n + node) * D + gl * 8);
  bf16x8 qv3 = *(const bf16x8*)(P + ((size_t)3 * n + node) * D + gl * 8);
  bf16x8 qv4 = *(const bf16x8*)(P + ((size_t)4 * n + node) * D + gl * 8);

  const bf16x8 KZ = {};
  float m = -1e30f, den = 0.f;
  float a[8];
#pragma unroll
  for (int i = 0; i < 8; ++i) a[i] = 0.f;

  int beg = offs[node], end = offs[node + 1];

  uint_t pvA[4], pvB[4];
  bf16x8 kvA[4], kvB[4];
  LOAD_CHUNK(pvA, kvA, beg)
  for (int j0 = beg; j0 < end; j0 += 8) {
    LOAD_CHUNK(pvB, kvB, j0 + 4)
    COMPUTE_CHUNK(pvA, kvA, j0)
    LOAD_CHUNK(pvA, kvA, j0 + 8)
    COMPUTE_CHUNK(pvB, kvB, j0 + 4)
  }

  float inv = (end > beg) ? 1.f / den : 0.f;
  const float* xr = x + (size_t)node * D + gl * 8;
  float* orow = out + (size_t)node * D + gl * 8;
  float4 xa = *(const float4*)xr;
  float4 xb = *(const float4*)(xr + 4);
  float4 oa, ob;
  oa.x = xa.x + a[0] * inv; oa.y = xa.y + a[1] * inv;
  oa.z = xa.z + a[2] * inv; oa.w = xa.w + a[3] * inv;
  ob.x = xb.x + a[4] * inv; ob.y = xb.y + a[5] * inv;
  ob.z = xb.z + a[6] * inv; ob.w = xb.w + a[7] * inv;
  *(float4*)orow = oa;
  *(float4*)(orow + 4) = ob;
}

// ---------------------------------------------------------------------------
// K5: fused LN2 + FFN + residual via MFMA, in-place on out (holds x2).
// Weight-hi only: 2-term GEMMs, half the weight loads.
// ---------------------------------------------------------------------------
__global__ __launch_bounds__(256, 3) void ffn_mfma_kernel(
    const ushort_t* __restrict__ w1h, const ushort_t* __restrict__ w2h,
    const float* __restrict__ b1, const float* __restrict__ b2,
    const float* __restrict__ g, const float* __restrict__ bln,
    float* __restrict__ out, int n) {
  __shared__ ushort_t z2h[64 * D];
  __shared__ ushort_t z2l[64 * D];
  __shared__ float hmb[4][16 * 36];
  int tid = threadIdx.x, w = tid >> 6, l = tid & 63;
  int n0 = blockIdx.x * 64;

  for (int i = w; i < 64; i += 4) {
    int r = n0 + i;
    float v0 = 0.f, v1 = 0.f;
    if (r < n) {
      v0 = out[(size_t)r * D + l];
      v1 = out[(size_t)r * D + 64 + l];
    }
    float s = v0 + v1, ss = v0 * v0 + v1 * v1;
    for (int o = 32; o; o >>= 1) { s += __shfl_xor(s, o); ss += __shfl_xor(ss, o); }
    float mu = s * (1.f / D);
    float var = ss * (1.f / D) - mu * mu;
    float rs = rsqrtf(var + LN_EPS);
    float z0 = (v0 - mu) * rs * g[l] + bln[l];
    float z1 = (v1 - mu) * rs * g[l + 64] + bln[l + 64];
    int sw = (i & 7) << 3;
    int e0 = (i * D + l) ^ sw;
    int e1 = (i * D + l + 64) ^ sw;
    __bf16 h0 = (__bf16)z0, h1 = (__bf16)z1;
    z2h[e0] = __builtin_bit_cast(ushort_t, h0);
    z2h[e1] = __builtin_bit_cast(ushort_t, h1);
    __bf16 l0 = (__bf16)(z0 - (float)h0), l1 = (__bf16)(z1 - (float)h1);
    z2l[e0] = __builtin_bit_cast(ushort_t, l0);
    z2l[e1] = __builtin_bit_cast(ushort_t, l1);
  }
  __syncthreads();

  int lrow = w * 16 + (l & 15);
  int koff = (l >> 4) * 8;
  bf16x8 ah[4], al[4];
#pragma unroll
  for (int kk = 0; kk < 4; ++kk) {
    int e = (lrow * D + kk * 32 + koff) ^ ((lrow & 7) << 3);
    ah[kk] = *(const bf16x8*)(z2h + e);
    al[kk] = *(const bf16x8*)(z2l + e);
  }

  int col16 = l & 15, rgrp = (l >> 4) * 4;
  f32x4 acc2[8];
#pragma unroll
  for (int c = 0; c < 8; ++c) acc2[c] = (f32x4){0.f, 0.f, 0.f, 0.f};
  float* hbp = &hmb[w][0];

  for (int kk2 = 0; kk2 < 16; ++kk2) {
    // ---- batched W1 hi-fragment loads (8 x dwordx4, all in flight)
    bf16x8 B1h[2][4];
#pragma unroll
    for (int cc = 0; cc < 2; ++cc)
#pragma unroll
      for (int kk = 0; kk < 4; ++kk) {
        size_t o = ((size_t)((kk2 * 2 + cc) * 4 + kk) * 64 + l) * 8;
        B1h[cc][kk] = *(const bf16x8*)(w1h + o);
      }
    // ---- Hm chunk: 4 independent chains of length 4
    f32x4 ha[2], hc[2];
#pragma unroll
    for (int cc = 0; cc < 2; ++cc) {
      float bias = b1[(kk2 * 2 + cc) * 16 + col16];
      ha[cc] = (f32x4){bias, bias, bias, bias};
      hc[cc] = (f32x4){0.f, 0.f, 0.f, 0.f};
    }
#pragma unroll
    for (int kk = 0; kk < 4; ++kk)
#pragma unroll
      for (int cc = 0; cc < 2; ++cc) {
        ha[cc] = __builtin_amdgcn_mfma_f32_16x16x32_bf16(ah[kk], B1h[cc][kk], ha[cc], 0, 0, 0);
        hc[cc] = __builtin_amdgcn_mfma_f32_16x16x32_bf16(al[kk], B1h[cc][kk], hc[cc], 0, 0, 0);
      }
    // ---- bounce through padded per-wave LDS tile (relu fused)
#pragma unroll
    for (int cc = 0; cc < 2; ++cc)
#pragma unroll
      for (int r = 0; r < 4; ++r)
        hbp[(rgrp + r) * 36 + cc * 16 + col16] =
            fmaxf(ha[cc][r] + hc[cc][r], 0.f);
    // ---- re-fragment (lane -> row=l&15, k=koff..koff+7), hi/lo split
    float av[8];
    *(float4*)&av[0] = *(const float4*)&hbp[(l & 15) * 36 + koff];
    *(float4*)&av[4] = *(const float4*)&hbp[(l & 15) * 36 + koff + 4];
    bf16x8 a2h, a2l;
#pragma unroll
    for (int j = 0; j < 8; ++j) {
      __bf16 hv = (__bf16)av[j];
      a2h[j] = hv;
      a2l[j] = (__bf16)(av[j] - (float)hv);
    }
    // ---- batched W2 hi-fragment loads (8 x dwordx4)
    bf16x8 B2h[8];
#pragma unroll
    for (int c2 = 0; c2 < 8; ++c2) {
      size_t o = ((size_t)(c2 * 16 + kk2) * 64 + l) * 8;
      B2h[c2] = *(const bf16x8*)(w2h + o);
    }
    // ---- second GEMM: 8 independent chains of 2
#pragma unroll
    for (int c2 = 0; c2 < 8; ++c2) {
      acc2[c2] = __builtin_amdgcn_mfma_f32_16x16x32_bf16(a2h, B2h[c2], acc2[c2], 0, 0, 0);
      acc2[c2] = __builtin_amdgcn_mfma_f32_16x16x32_bf16(a2l, B2h[c2], acc2[c2], 0, 0, 0);
    }
  }

#pragma unroll
  for (int c2 = 0; c2 < 8; ++c2) {
    float bias2 = b2[c2 * 16 + col16];
#pragma unroll
    for (int r = 0; r < 4; ++r) {
      int row = n0 + w * 16 + rgrp + r;
      if (row < n) {
        size_t o = (size_t)row * D + c2 * 16 + col16;
        out[o] = out[o] + acc2[c2][r] + bias2;
      }
    }
  }
}

// ---------------------------------------------------------------------------
extern "C" void kernel_launch(void* const* d_in, const int* in_sizes, int n_in,
                              void* d_out, int out_size, void* d_ws, size_t ws_size,
                              hipStream_t stream) {
  const float* x      = (const float*)d_in[0];
  const int* edges    = (const int*)d_in[1];
  const unsigned char* masks = (const unsigned char*)d_in[2];
  const float* Wk     = (const float*)d_in[3];
  const float* bk     = (const float*)d_in[4];
  const float* ln1_g  = (const float*)d_in[5];
  const float* ln1_b  = (const float*)d_in[6];
  const float* ln2_g  = (const float*)d_in[7];
  const float* ln2_b  = (const float*)d_in[8];
  const float* W1     = (const float*)d_in[9];
  const float* b1     = (const float*)d_in[10];
  const float* W2     = (const float*)d_in[11];
  const float* b2     = (const float*)d_in[12];
  float* out = (float*)d_out;

  const int n = in_sizes[0] / D;
  const int E = in_sizes[1] / 2;
  const int nb = (n + 1023) / 1024;

  // workspace layout (~68 MB)
  char* ws = (char*)d_ws;
  size_t off = 0;
  ushort_t* P = (ushort_t*)(ws + off);  off += (size_t)NTYPES * n * D * sizeof(ushort_t);
  int* cnt    = (int*)(ws + off);       off += (size_t)n * sizeof(int);
  int* offs   = (int*)(ws + off);       off += (size_t)(n + 1) * sizeof(int);
  int* cursor = (int*)(ws + off);       off += (size_t)n * sizeof(int);
  int* loc    = (int*)(ws + off);       off += (size_t)n * sizeof(int);
  int* bsums  = (int*)(ws + off);       off += (size_t)nb * sizeof(int);
  int* total  = (int*)(ws + off);       off += 64;
  uint_t* elist = (uint_t*)(ws + off);  off += (size_t)E * sizeof(uint_t);
  int* flag   = (int*)(ws + off);       off += 64;
  ushort_t* wkh = (ushort_t*)(ws + off); off += (size_t)NTYPES * D * D * sizeof(ushort_t);
  ushort_t* w1h = (ushort_t*)(ws + off); off += (size_t)D * FFDIM * sizeof(ushort_t);
  ushort_t* w2h = (ushort_t*)(ws + off); off += (size_t)FFDIM * D * sizeof(ushort_t);
  (void)ws_size; (void)n_in; (void)out_size;

  // z hi/lo parked in d_out (dead before attn writes x2 there)
  ushort_t* zh = (ushort_t*)out;
  ushort_t* zl = zh + (size_t)n * D;

  // K0: mask dtype detection
  detect_kernel<<<1, 64, 0, stream>>>(masks, E, flag);

  // K1: LN1 -> z hi/lo
  ln1_kernel<<<(n + 3) / 4, 256, 0, stream>>>(x, ln1_g, ln1_b, zh, zl, n);

  // K1b: weight fragment conversion (hi only)
  {
    dim3 gwk((8 * 4 * 64 + 255) / 256, NTYPES);
    conv_frag_kernel<<<gwk, 256, 0, stream>>>(Wk, wkh, D, D,
                                              (size_t)D * D, (size_t)D * D);
    dim3 gw1(((FFDIM / 16) * 4 * 64 + 255) / 256, 1);
    conv_frag_kernel<<<gw1, 256, 0, stream>>>(W1, w1h, D, FFDIM, 0, 0);
    dim3 gw2((8 * (FFDIM / 32) * 64 + 255) / 256, 1);
    conv_frag_kernel<<<gw2, 256, 0, stream>>>(W2, w2h, FFDIM, D, 0, 0);
  }

  // K2: projections
  proj_mfma_kernel<<<(n + 63) / 64, 256, 0, stream>>>(zh, zl, wkh, bk, P, n);

  // K3: CSR build by src (hierarchical scan)
  zero_kernel<<<(n + 255) / 256, 256, 0, stream>>>(cnt, n);
  hist_kernel<<<(E + 255) / 256, 256, 0, stream>>>(edges, cnt, E);
  scanA_kernel<<<nb, 256, 0, stream>>>(cnt, loc, bsums, n);
  scanB_kernel<<<1, 256, 0, stream>>>(bsums, nb, total);
  scanC_kernel<<<(n + 255) / 256, 256, 0, stream>>>(loc, bsums, total, offs, cursor, n);
  fill_kernel<<<(E + 255) / 256, 256, 0, stream>>>(edges, masks, flag, cursor, elist, E);

  // K4: attention -> out = x + attn
  attn_kernel<<<(n + 15) / 16, 256, 0, stream>>>(x, P, offs, elist, out, n);

  // K5: LN2 + FFN + residual
  ffn_mfma_kernel<<<(n + 63) / 64, 256, 0, stream>>>(w1h, w2h,
                                                     b1, b2, ln2_g, ln2_b, out, n);
}

// Round 8
// 278.517 us; speedup vs baseline: 1.2078x; 1.0691x over previous
//
#include <hip/hip_runtime.h>

// Problem constants (match reference)
#define D 128
#define H 8
#define DK 16
#define FFDIM 512
#define NTYPES 5
#define LN_EPS 1e-5f

typedef __bf16 bf16x8 __attribute__((ext_vector_type(8)));
typedef float f32x4 __attribute__((ext_vector_type(4)));
typedef unsigned short ushort_t;
typedef unsigned int uint_t;

__device__ inline ushort_t bfbits(float f) {
  __bf16 b = (__bf16)f;
  return __builtin_bit_cast(ushort_t, b);
}

// ---------------------------------------------------------------------------
// K0: detect mask dtype (byte-bool vs int32). flag=1 for byte masks.
// ---------------------------------------------------------------------------
__global__ void detect_kernel(const unsigned char* __restrict__ m8, int E,
                              int* __restrict__ flag) {
  int lane = threadIdx.x;  // 64 threads, 1 wave
  int s = 1;
  if (lane < E) {
    s = 0;
#pragma unroll
    for (int i = 0; i < NTYPES; ++i) s += (m8[(size_t)i * E + lane] != 0);
  }
  unsigned long long b = __ballot(s == 1);
  if (lane == 0) *flag = (b == ~0ull) ? 1 : 0;
}

__device__ inline int decode_etype(const unsigned char* __restrict__ m8,
                                   int E, int e, int is8) {
  int t = 0;
  if (is8) {
#pragma unroll
    for (int i = 1; i < NTYPES; ++i) t += i * (m8[(size_t)i * E + e] != 0);
  } else {
    const int* m32 = (const int*)m8;
#pragma unroll
    for (int i = 1; i < NTYPES; ++i) t += i * (m32[(size_t)i * E + e] != 0);
  }
  return t > (NTYPES - 1) ? (NTYPES - 1) : t;
}

// ---------------------------------------------------------------------------
// K1: LayerNorm x -> z, stored as hi/lo bf16 split (parked in d_out)
// ---------------------------------------------------------------------------
__global__ __launch_bounds__(256) void ln1_kernel(
    const float* __restrict__ x, const float* __restrict__ g,
    const float* __restrict__ b, ushort_t* __restrict__ zh,
    ushort_t* __restrict__ zl, int n) {
  int row = blockIdx.x * 4 + (threadIdx.x >> 6);
  int lane = threadIdx.x & 63;
  if (row >= n) return;
  const float* xr = x + (size_t)row * D;
  float v0 = xr[lane], v1 = xr[lane + 64];
  float s = v0 + v1, ss = v0 * v0 + v1 * v1;
  for (int o = 32; o; o >>= 1) { s += __shfl_xor(s, o); ss += __shfl_xor(ss, o); }
  float mu = s * (1.f / D);
  float var = ss * (1.f / D) - mu * mu;
  float rs = rsqrtf(var + LN_EPS);
  float z0 = (v0 - mu) * rs * g[lane] + b[lane];
  float z1 = (v1 - mu) * rs * g[lane + 64] + b[lane + 64];
  size_t o0 = (size_t)row * D + lane, o1 = o0 + 64;
  __bf16 h0 = (__bf16)z0, h1 = (__bf16)z1;
  zh[o0] = __builtin_bit_cast(ushort_t, h0);
  zh[o1] = __builtin_bit_cast(ushort_t, h1);
  __bf16 l0 = (__bf16)(z0 - (float)h0), l1 = (__bf16)(z1 - (float)h1);
  zl[o0] = __builtin_bit_cast(ushort_t, l0);
  zl[o1] = __builtin_bit_cast(ushort_t, l1);
}

// ---------------------------------------------------------------------------
// K1b: convert a row-major f32 weight [K][N] into MFMA B-fragment order, bf16 hi.
// ---------------------------------------------------------------------------
__global__ void conv_frag_kernel(const float* __restrict__ W,
                                 ushort_t* __restrict__ hi,
                                 int K, int Ncol, size_t matW, size_t matF) {
  int gid = blockIdx.x * 256 + threadIdx.x;
  int total = (Ncol / 16) * (K / 32) * 64;
  if (gid >= total) return;
  const float* Wm = W + (size_t)blockIdx.y * matW;
  ushort_t* him = hi + (size_t)blockIdx.y * matF;
  int l = gid & 63;
  int ck = gid >> 6;
  int kk = ck % (K / 32);
  int c = ck / (K / 32);
  int row0 = kk * 32 + (l >> 4) * 8;
  int col = c * 16 + (l & 15);
  size_t ob = (size_t)gid * 8;
#pragma unroll
  for (int j = 0; j < 8; ++j) {
    float w = Wm[(size_t)(row0 + j) * Ncol + col];
    __bf16 h = (__bf16)w;
    him[ob + j] = __builtin_bit_cast(ushort_t, h);
  }
}

// ---------------------------------------------------------------------------
// K2: proj via MFMA: P[t][node][d] = bf16( (zh+zl) @ Wkh[t] + bk[t] )
// ---------------------------------------------------------------------------
__global__ __launch_bounds__(256, 3) void proj_mfma_kernel(
    const ushort_t* __restrict__ zh, const ushort_t* __restrict__ zl,
    const ushort_t* __restrict__ wkh,
    const float* __restrict__ bk, ushort_t* __restrict__ P, int n) {
  int w = threadIdx.x >> 6, l = threadIdx.x & 63;
  int n0 = blockIdx.x * 64 + w * 16;
  int arow = n0 + (l & 15);
  if (arow >= n) arow = n - 1;
  int koff = (l >> 4) * 8;
  bf16x8 ah[4], al[4];
#pragma unroll
  for (int kk = 0; kk < 4; ++kk) {
    size_t zo = (size_t)arow * D + kk * 32 + koff;
    ah[kk] = *(const bf16x8*)(zh + zo);
    al[kk] = *(const bf16x8*)(zl + zo);
  }
  int col16 = l & 15, rgrp = (l >> 4) * 4;
  for (int t = 0; t < NTYPES; ++t) {
    const ushort_t* bh0 = wkh + (size_t)t * (D * D);
    ushort_t* Pt = P + (size_t)t * n * D;
#pragma unroll
    for (int cp = 0; cp < 4; ++cp) {
      bf16x8 Bh[2][4];
#pragma unroll
      for (int cc = 0; cc < 2; ++cc)
#pragma unroll
        for (int kk = 0; kk < 4; ++kk) {
          size_t o = ((size_t)((cp * 2 + cc) * 4 + kk) * 64 + l) * 8;
          Bh[cc][kk] = *(const bf16x8*)(bh0 + o);
        }
      f32x4 aa[2], ac[2];
#pragma unroll
      for (int cc = 0; cc < 2; ++cc) {
        float bias = bk[t * D + (cp * 2 + cc) * 16 + col16];
        aa[cc] = (f32x4){bias, bias, bias, bias};
        ac[cc] = (f32x4){0.f, 0.f, 0.f, 0.f};
      }
#pragma unroll
      for (int kk = 0; kk < 4; ++kk)
#pragma unroll
        for (int cc = 0; cc < 2; ++cc) {
          aa[cc] = __builtin_amdgcn_mfma_f32_16x16x32_bf16(ah[kk], Bh[cc][kk], aa[cc], 0, 0, 0);
          ac[cc] = __builtin_amdgcn_mfma_f32_16x16x32_bf16(al[kk], Bh[cc][kk], ac[cc], 0, 0, 0);
        }
#pragma unroll
      for (int cc = 0; cc < 2; ++cc)
#pragma unroll
        for (int r = 0; r < 4; ++r) {
          int row = n0 + rgrp + r;
          if (row < n)
            Pt[(size_t)row * D + (cp * 2 + cc) * 16 + col16] =
                bfbits(aa[cc][r] + ac[cc][r]);
        }
    }
  }
}

// ---------------------------------------------------------------------------
// K3: typed-CSR build by (src, etype)
// ---------------------------------------------------------------------------
__global__ void zero_kernel(int* __restrict__ p, int n) {
  int i = blockIdx.x * 256 + threadIdx.x;
  if (i < n) p[i] = 0;
}

// per-(src,type) histogram + etype cache
__global__ void hist5_kernel(const int* __restrict__ edges,
                             const unsigned char* __restrict__ masks,
                             const int* __restrict__ flag,
                             int* __restrict__ cnt5,
                             unsigned char* __restrict__ etype8, int E) {
  int e = blockIdx.x * 256 + threadIdx.x;
  if (e >= E) return;
  int t = decode_etype(masks, E, e, *flag);
  etype8[e] = (unsigned char)t;
  atomicAdd(&cnt5[edges[e] * 8 + t], 1);
}

// scanA5: 1 node/thread; node total = sum of its 5 type counts
__global__ __launch_bounds__(256) void scanA5_kernel(const int* __restrict__ cnt5,
                                                     int* __restrict__ loc,
                                                     int* __restrict__ bsums, int n) {
  __shared__ int ts[256];
  int tid = threadIdx.x;
  int i = blockIdx.x * 256 + tid;
  int v = 0;
  if (i < n) {
    int4 c0 = *(const int4*)(cnt5 + (size_t)i * 8);
    v = c0.x + c0.y + c0.z + c0.w + cnt5[(size_t)i * 8 + 4];
  }
  ts[tid] = v;
  __syncthreads();
  for (int o = 1; o < 256; o <<= 1) {
    int t = (tid >= o) ? ts[tid - o] : 0;
    __syncthreads();
    ts[tid] += t;
    __syncthreads();
  }
  if (i < n) loc[i] = ts[tid] - v;
  if (tid == 255) bsums[blockIdx.x] = ts[255];
}

__global__ __launch_bounds__(256) void scanB_kernel(int* __restrict__ bsums, int nb,
                                                    int* __restrict__ total) {
  __shared__ int ts[256];
  int tid = threadIdx.x;
  int per = (nb + 255) / 256;
  int start = tid * per;
  int end = min(start + per, nb);
  int s = 0;
  for (int i = start; i < end; ++i) s += bsums[i];
  ts[tid] = s;
  __syncthreads();
  for (int o = 1; o < 256; o <<= 1) {
    int t = (tid >= o) ? ts[tid - o] : 0;
    __syncthreads();
    ts[tid] += t;
    __syncthreads();
  }
  int run = ts[tid] - s;
  for (int i = start; i < end; ++i) {
    int v = bsums[i];
    bsums[i] = run;
    run += v;
  }
  if (tid == 255) *total = ts[255];
}

__global__ void scanC_kernel(const int* __restrict__ loc,
                             const int* __restrict__ bsums,
                             const int* __restrict__ total,
                             int* __restrict__ offs, int n) {
  int i = blockIdx.x * 256 + threadIdx.x;
  if (i < n) offs[i] = loc[i] + bsums[i >> 8];
  if (i == 0) offs[n] = *total;
}

// build per-node typed run boundaries tb[node*8 + t] (t=0..5) and cursors
__global__ void build5_kernel(const int* __restrict__ offs,
                              const int* __restrict__ cnt5,
                              int* __restrict__ cursor5, int* __restrict__ tb,
                              int n) {
  int i = blockIdx.x * 256 + threadIdx.x;
  if (i >= n) return;
  int base = offs[i];
#pragma unroll
  for (int t = 0; t < NTYPES; ++t) {
    int c = cnt5[(size_t)i * 8 + t];
    cursor5[(size_t)i * 8 + t] = base;
    tb[(size_t)i * 8 + t] = base;
    base += c;
  }
  tb[(size_t)i * 8 + 5] = base;
}

// fill: elist[pos] = t*n + dst  (direct P row index, decode-free)
__global__ void fill_kernel(const int* __restrict__ edges,
                            const unsigned char* __restrict__ etype8,
                            int* __restrict__ cursor5,
                            int* __restrict__ elist, int E, int n) {
  int e = blockIdx.x * 256 + threadIdx.x;
  if (e >= E) return;
  int t = etype8[e];
  int dst = edges[E + e];
  int pos = atomicAdd(&cursor5[edges[e] * 8 + t], 1);
  elist[pos] = t * n + dst;
}

// ---------------------------------------------------------------------------
// K4: per-node attention over type-sorted runs. 16 lanes/node, 4 nodes/wave.
// q loaded+converted once per (node,type) run; single-edge online softmax
// with depth-1 k prefetch. elist holds direct P row index.
// ---------------------------------------------------------------------------
__global__ __launch_bounds__(256, 4) void attn_kernel(
    const float* __restrict__ x, const ushort_t* __restrict__ P,
    const int* __restrict__ tb, const int* __restrict__ elist,
    float* __restrict__ out, int n) {
  int node = (blockIdx.x * 256 + threadIdx.x) >> 4;
  int gl = threadIdx.x & 15;
  if (node >= n) return;

  int4 t03 = *(const int4*)(tb + (size_t)node * 8);
  int2 t45 = *(const int2*)(tb + (size_t)node * 8 + 4);
  int bnd0 = t03.x, bnd1 = t03.y, bnd2 = t03.z, bnd3 = t03.w;
  int bnd4 = t45.x, bnd5 = t45.y;

  float m = -1e30f, den = 0.f;
  float a[8];
#pragma unroll
  for (int i = 0; i < 8; ++i) a[i] = 0.f;

#pragma unroll
  for (int t = 0; t < NTYPES; ++t) {
    int jb = (t == 0) ? bnd0 : (t == 1) ? bnd1 : (t == 2) ? bnd2
             : (t == 3) ? bnd3 : bnd4;
    int je = (t == 0) ? bnd1 : (t == 1) ? bnd2 : (t == 2) ? bnd3
             : (t == 3) ? bnd4 : bnd5;
    if (jb >= je) continue;
    // q row for this (type, node), converted once per run
    bf16x8 qb = *(const bf16x8*)(P + (size_t)(t * n + node) * D + gl * 8);
    float qf[8];
#pragma unroll
    for (int d = 0; d < 8; ++d) qf[d] = (float)qb[d];

    int row = elist[jb];
    bf16x8 kv = *(const bf16x8*)(P + (size_t)row * D + gl * 8);
    for (int j = jb; j < je; ++j) {
      bf16x8 kvn = kv;
      if (j + 1 < je) {
        int rn = elist[j + 1];
        kvn = *(const bf16x8*)(P + (size_t)rn * D + gl * 8);
      }
      float kf[8], p = 0.f;
#pragma unroll
      for (int d = 0; d < 8; ++d) {
        kf[d] = (float)kv[d];
        p += qf[d] * kf[d];
      }
      p += __shfl_xor(p, 1);  // 16 dims/head = 2 lanes
      float nm = fmaxf(m, p);
      float sc = __expf(m - nm);
      float w = __expf(p - nm);
      den = den * sc + w;
#pragma unroll
      for (int d = 0; d < 8; ++d) a[d] = a[d] * sc + w * kf[d];
      m = nm;
      kv = kvn;
    }
  }

  float inv = (bnd5 > bnd0) ? 1.f / den : 0.f;
  const float* xr = x + (size_t)node * D + gl * 8;
  float* orow = out + (size_t)node * D + gl * 8;
  float4 xa = *(const float4*)xr;
  float4 xb = *(const float4*)(xr + 4);
  float4 oa, ob;
  oa.x = xa.x + a[0] * inv; oa.y = xa.y + a[1] * inv;
  oa.z = xa.z + a[2] * inv; oa.w = xa.w + a[3] * inv;
  ob.x = xb.x + a[4] * inv; ob.y = xb.y + a[5] * inv;
  ob.z = xb.z + a[6] * inv; ob.w = xb.w + a[7] * inv;
  *(float4*)orow = oa;
  *(float4*)(orow + 4) = ob;
}

// ---------------------------------------------------------------------------
// K5: fused LN2 + FFN + residual via MFMA, in-place on out (holds x2).
// ---------------------------------------------------------------------------
__global__ __launch_bounds__(256, 3) void ffn_mfma_kernel(
    const ushort_t* __restrict__ w1h, const ushort_t* __restrict__ w2h,
    const float* __restrict__ b1, const float* __restrict__ b2,
    const float* __restrict__ g, const float* __restrict__ bln,
    float* __restrict__ out, int n) {
  __shared__ ushort_t z2h[64 * D];
  __shared__ ushort_t z2l[64 * D];
  __shared__ float hmb[4][16 * 36];
  int tid = threadIdx.x, w = tid >> 6, l = tid & 63;
  int n0 = blockIdx.x * 64;

  for (int i = w; i < 64; i += 4) {
    int r = n0 + i;
    float v0 = 0.f, v1 = 0.f;
    if (r < n) {
      v0 = out[(size_t)r * D + l];
      v1 = out[(size_t)r * D + 64 + l];
    }
    float s = v0 + v1, ss = v0 * v0 + v1 * v1;
    for (int o = 32; o; o >>= 1) { s += __shfl_xor(s, o); ss += __shfl_xor(ss, o); }
    float mu = s * (1.f / D);
    float var = ss * (1.f / D) - mu * mu;
    float rs = rsqrtf(var + LN_EPS);
    float z0 = (v0 - mu) * rs * g[l] + bln[l];
    float z1 = (v1 - mu) * rs * g[l + 64] + bln[l + 64];
    int sw = (i & 7) << 3;
    int e0 = (i * D + l) ^ sw;
    int e1 = (i * D + l + 64) ^ sw;
    __bf16 h0 = (__bf16)z0, h1 = (__bf16)z1;
    z2h[e0] = __builtin_bit_cast(ushort_t, h0);
    z2h[e1] = __builtin_bit_cast(ushort_t, h1);
    __bf16 l0 = (__bf16)(z0 - (float)h0), l1 = (__bf16)(z1 - (float)h1);
    z2l[e0] = __builtin_bit_cast(ushort_t, l0);
    z2l[e1] = __builtin_bit_cast(ushort_t, l1);
  }
  __syncthreads();

  int lrow = w * 16 + (l & 15);
  int koff = (l >> 4) * 8;
  bf16x8 ah[4], al[4];
#pragma unroll
  for (int kk = 0; kk < 4; ++kk) {
    int e = (lrow * D + kk * 32 + koff) ^ ((lrow & 7) << 3);
    ah[kk] = *(const bf16x8*)(z2h + e);
    al[kk] = *(const bf16x8*)(z2l + e);
  }

  int col16 = l & 15, rgrp = (l >> 4) * 4;
  f32x4 acc2[8];
#pragma unroll
  for (int c = 0; c < 8; ++c) acc2[c] = (f32x4){0.f, 0.f, 0.f, 0.f};
  float* hbp = &hmb[w][0];

  for (int kk2 = 0; kk2 < 16; ++kk2) {
    bf16x8 B1h[2][4];
#pragma unroll
    for (int cc = 0; cc < 2; ++cc)
#pragma unroll
      for (int kk = 0; kk < 4; ++kk) {
        size_t o = ((size_t)((kk2 * 2 + cc) * 4 + kk) * 64 + l) * 8;
        B1h[cc][kk] = *(const bf16x8*)(w1h + o);
      }
    f32x4 ha[2], hc[2];
#pragma unroll
    for (int cc = 0; cc < 2; ++cc) {
      float bias = b1[(kk2 * 2 + cc) * 16 + col16];
      ha[cc] = (f32x4){bias, bias, bias, bias};
      hc[cc] = (f32x4){0.f, 0.f, 0.f, 0.f};
    }
#pragma unroll
    for (int kk = 0; kk < 4; ++kk)
#pragma unroll
      for (int cc = 0; cc < 2; ++cc) {
        ha[cc] = __builtin_amdgcn_mfma_f32_16x16x32_bf16(ah[kk], B1h[cc][kk], ha[cc], 0, 0, 0);
        hc[cc] = __builtin_amdgcn_mfma_f32_16x16x32_bf16(al[kk], B1h[cc][kk], hc[cc], 0, 0, 0);
      }
#pragma unroll
    for (int cc = 0; cc < 2; ++cc)
#pragma unroll
      for (int r = 0; r < 4; ++r)
        hbp[(rgrp + r) * 36 + cc * 16 + col16] =
            fmaxf(ha[cc][r] + hc[cc][r], 0.f);
    float av[8];
    *(float4*)&av[0] = *(const float4*)&hbp[(l & 15) * 36 + koff];
    *(float4*)&av[4] = *(const float4*)&hbp[(l & 15) * 36 + koff + 4];
    bf16x8 a2h, a2l;
#pragma unroll
    for (int j = 0; j < 8; ++j) {
      __bf16 hv = (__bf16)av[j];
      a2h[j] = hv;
      a2l[j] = (__bf16)(av[j] - (float)hv);
    }
    bf16x8 B2h[8];
#pragma unroll
    for (int c2 = 0; c2 < 8; ++c2) {
      size_t o = ((size_t)(c2 * 16 + kk2) * 64 + l) * 8;
      B2h[c2] = *(const bf16x8*)(w2h + o);
    }
#pragma unroll
    for (int c2 = 0; c2 < 8; ++c2) {
      acc2[c2] = __builtin_amdgcn_mfma_f32_16x16x32_bf16(a2h, B2h[c2], acc2[c2], 0, 0, 0);
      acc2[c2] = __builtin_amdgcn_mfma_f32_16x16x32_bf16(a2l, B2h[c2], acc2[c2], 0, 0, 0);
    }
  }

#pragma unroll
  for (int c2 = 0; c2 < 8; ++c2) {
    float bias2 = b2[c2 * 16 + col16];
#pragma unroll
    for (int r = 0; r < 4; ++r) {
      int row = n0 + w * 16 + rgrp + r;
      if (row < n) {
        size_t o = (size_t)row * D + c2 * 16 + col16;
        out[o] = out[o] + acc2[c2][r] + bias2;
      }
    }
  }
}

// ---------------------------------------------------------------------------
extern "C" void kernel_launch(void* const* d_in, const int* in_sizes, int n_in,
                              void* d_out, int out_size, void* d_ws, size_t ws_size,
                              hipStream_t stream) {
  const float* x      = (const float*)d_in[0];
  const int* edges    = (const int*)d_in[1];
  const unsigned char* masks = (const unsigned char*)d_in[2];
  const float* Wk     = (const float*)d_in[3];
  const float* bk     = (const float*)d_in[4];
  const float* ln1_g  = (const float*)d_in[5];
  const float* ln1_b  = (const float*)d_in[6];
  const float* ln2_g  = (const float*)d_in[7];
  const float* ln2_b  = (const float*)d_in[8];
  const float* W1     = (const float*)d_in[9];
  const float* b1     = (const float*)d_in[10];
  const float* W2     = (const float*)d_in[11];
  const float* b2     = (const float*)d_in[12];
  float* out = (float*)d_out;

  const int n = in_sizes[0] / D;
  const int E = in_sizes[1] / 2;
  const int nbn = (n + 255) / 256;  // scanA5 blocks (1 node/thread)

  // workspace layout (~74 MB)
  char* ws = (char*)d_ws;
  size_t off = 0;
  ushort_t* P = (ushort_t*)(ws + off);  off += (size_t)NTYPES * n * D * sizeof(ushort_t);
  int* cnt5   = (int*)(ws + off);       off += (size_t)n * 8 * sizeof(int);
  int* cursor5= (int*)(ws + off);       off += (size_t)n * 8 * sizeof(int);
  int* tb     = (int*)(ws + off);       off += (size_t)n * 8 * sizeof(int);
  int* offs   = (int*)(ws + off);       off += (size_t)(n + 1) * sizeof(int);
  int* loc    = (int*)(ws + off);       off += (size_t)n * sizeof(int);
  int* bsums  = (int*)(ws + off);       off += (size_t)nbn * sizeof(int);
  int* total  = (int*)(ws + off);       off += 64;
  int* elist  = (int*)(ws + off);       off += (size_t)E * sizeof(int);
  unsigned char* etype8 = (unsigned char*)(ws + off); off += (size_t)E + 64;
  int* flag   = (int*)(ws + off);       off += 64;
  ushort_t* wkh = (ushort_t*)(ws + off); off += (size_t)NTYPES * D * D * sizeof(ushort_t);
  ushort_t* w1h = (ushort_t*)(ws + off); off += (size_t)D * FFDIM * sizeof(ushort_t);
  ushort_t* w2h = (ushort_t*)(ws + off); off += (size_t)FFDIM * D * sizeof(ushort_t);
  (void)ws_size; (void)n_in; (void)out_size;

  // z hi/lo parked in d_out (dead before attn writes x2 there)
  ushort_t* zh = (ushort_t*)out;
  ushort_t* zl = zh + (size_t)n * D;

  // K0: mask dtype detection
  detect_kernel<<<1, 64, 0, stream>>>(masks, E, flag);

  // K1: LN1 -> z hi/lo
  ln1_kernel<<<(n + 3) / 4, 256, 0, stream>>>(x, ln1_g, ln1_b, zh, zl, n);

  // K1b: weight fragment conversion (hi only)
  {
    dim3 gwk((8 * 4 * 64 + 255) / 256, NTYPES);
    conv_frag_kernel<<<gwk, 256, 0, stream>>>(Wk, wkh, D, D,
                                              (size_t)D * D, (size_t)D * D);
    dim3 gw1(((FFDIM / 16) * 4 * 64 + 255) / 256, 1);
    conv_frag_kernel<<<gw1, 256, 0, stream>>>(W1, w1h, D, FFDIM, 0, 0);
    dim3 gw2((8 * (FFDIM / 32) * 64 + 255) / 256, 1);
    conv_frag_kernel<<<gw2, 256, 0, stream>>>(W2, w2h, FFDIM, D, 0, 0);
  }

  // K2: projections
  proj_mfma_kernel<<<(n + 63) / 64, 256, 0, stream>>>(zh, zl, wkh, bk, P, n);

  // K3: typed-CSR build
  zero_kernel<<<(n * 8 + 255) / 256, 256, 0, stream>>>(cnt5, n * 8);
  hist5_kernel<<<(E + 255) / 256, 256, 0, stream>>>(edges, masks, flag, cnt5, etype8, E);
  scanA5_kernel<<<nbn, 256, 0, stream>>>(cnt5, loc, bsums, n);
  scanB_kernel<<<1, 256, 0, stream>>>(bsums, nbn, total);
  scanC_kernel<<<(n + 255) / 256, 256, 0, stream>>>(loc, bsums, total, offs, n);
  build5_kernel<<<(n + 255) / 256, 256, 0, stream>>>(offs, cnt5, cursor5, tb, n);
  fill_kernel<<<(E + 255) / 256, 256, 0, stream>>>(edges, etype8, cursor5, elist, E, n);

  // K4: attention -> out = x + attn
  attn_kernel<<<(n + 15) / 16, 256, 0, stream>>>(x, P, tb, elist, out, n);

  // K5: LN2 + FFN + residual
  ffn_mfma_kernel<<<(n + 63) / 64, 256, 0, stream>>>(w1h, w2h,
                                                     b1, b2, ln2_g, ln2_b, out, n);
}

// Round 9
// 261.206 us; speedup vs baseline: 1.2879x; 1.0663x over previous
//
#include <hip/hip_runtime.h>

// Problem constants (match reference)
#define D 128
#define H 8
#define DK 16
#define FFDIM 512
#define NTYPES 5
#define LN_EPS 1e-5f

typedef __bf16 bf16x8 __attribute__((ext_vector_type(8)));
typedef float f32x4 __attribute__((ext_vector_type(4)));
typedef unsigned short ushort_t;
typedef unsigned int uint_t;

__device__ inline ushort_t bfbits(float f) {
  __bf16 b = (__bf16)f;
  return __builtin_bit_cast(ushort_t, b);
}

// ---------------------------------------------------------------------------
// K0: detect mask dtype (byte-bool vs int32). flag=1 for byte masks.
// ---------------------------------------------------------------------------
__global__ void detect_kernel(const unsigned char* __restrict__ m8, int E,
                              int* __restrict__ flag) {
  int lane = threadIdx.x;  // 64 threads, 1 wave
  int s = 1;
  if (lane < E) {
    s = 0;
#pragma unroll
    for (int i = 0; i < NTYPES; ++i) s += (m8[(size_t)i * E + lane] != 0);
  }
  unsigned long long b = __ballot(s == 1);
  if (lane == 0) *flag = (b == ~0ull) ? 1 : 0;
}

__device__ inline int decode_etype(const unsigned char* __restrict__ m8,
                                   int E, int e, int is8) {
  int t = 0;
  if (is8) {
#pragma unroll
    for (int i = 1; i < NTYPES; ++i) t += i * (m8[(size_t)i * E + e] != 0);
  } else {
    const int* m32 = (const int*)m8;
#pragma unroll
    for (int i = 1; i < NTYPES; ++i) t += i * (m32[(size_t)i * E + e] != 0);
  }
  return t > (NTYPES - 1) ? (NTYPES - 1) : t;
}

// ---------------------------------------------------------------------------
// K1: LayerNorm x -> z, stored as hi/lo bf16 split (parked in d_out)
// ---------------------------------------------------------------------------
__global__ __launch_bounds__(256) void ln1_kernel(
    const float* __restrict__ x, const float* __restrict__ g,
    const float* __restrict__ b, ushort_t* __restrict__ zh,
    ushort_t* __restrict__ zl, int n) {
  int row = blockIdx.x * 4 + (threadIdx.x >> 6);
  int lane = threadIdx.x & 63;
  if (row >= n) return;
  const float* xr = x + (size_t)row * D;
  float v0 = xr[lane], v1 = xr[lane + 64];
  float s = v0 + v1, ss = v0 * v0 + v1 * v1;
  for (int o = 32; o; o >>= 1) { s += __shfl_xor(s, o); ss += __shfl_xor(ss, o); }
  float mu = s * (1.f / D);
  float var = ss * (1.f / D) - mu * mu;
  float rs = rsqrtf(var + LN_EPS);
  float z0 = (v0 - mu) * rs * g[lane] + b[lane];
  float z1 = (v1 - mu) * rs * g[lane + 64] + b[lane + 64];
  size_t o0 = (size_t)row * D + lane, o1 = o0 + 64;
  __bf16 h0 = (__bf16)z0, h1 = (__bf16)z1;
  zh[o0] = __builtin_bit_cast(ushort_t, h0);
  zh[o1] = __builtin_bit_cast(ushort_t, h1);
  __bf16 l0 = (__bf16)(z0 - (float)h0), l1 = (__bf16)(z1 - (float)h1);
  zl[o0] = __builtin_bit_cast(ushort_t, l0);
  zl[o1] = __builtin_bit_cast(ushort_t, l1);
}

// ---------------------------------------------------------------------------
// K1b: convert a row-major f32 weight [K][N] into MFMA B-fragment order, bf16 hi.
// ---------------------------------------------------------------------------
__global__ void conv_frag_kernel(const float* __restrict__ W,
                                 ushort_t* __restrict__ hi,
                                 int K, int Ncol, size_t matW, size_t matF) {
  int gid = blockIdx.x * 256 + threadIdx.x;
  int total = (Ncol / 16) * (K / 32) * 64;
  if (gid >= total) return;
  const float* Wm = W + (size_t)blockIdx.y * matW;
  ushort_t* him = hi + (size_t)blockIdx.y * matF;
  int l = gid & 63;
  int ck = gid >> 6;
  int kk = ck % (K / 32);
  int c = ck / (K / 32);
  int row0 = kk * 32 + (l >> 4) * 8;
  int col = c * 16 + (l & 15);
  size_t ob = (size_t)gid * 8;
#pragma unroll
  for (int j = 0; j < 8; ++j) {
    float w = Wm[(size_t)(row0 + j) * Ncol + col];
    __bf16 h = (__bf16)w;
    him[ob + j] = __builtin_bit_cast(ushort_t, h);
  }
}

// ---------------------------------------------------------------------------
// K2: proj via MFMA: P[t][node][d] = bf16( (zh+zl) @ Wkh[t] + bk[t] )
// ---------------------------------------------------------------------------
__global__ __launch_bounds__(256, 3) void proj_mfma_kernel(
    const ushort_t* __restrict__ zh, const ushort_t* __restrict__ zl,
    const ushort_t* __restrict__ wkh,
    const float* __restrict__ bk, ushort_t* __restrict__ P, int n) {
  int w = threadIdx.x >> 6, l = threadIdx.x & 63;
  int n0 = blockIdx.x * 64 + w * 16;
  int arow = n0 + (l & 15);
  if (arow >= n) arow = n - 1;
  int koff = (l >> 4) * 8;
  bf16x8 ah[4], al[4];
#pragma unroll
  for (int kk = 0; kk < 4; ++kk) {
    size_t zo = (size_t)arow * D + kk * 32 + koff;
    ah[kk] = *(const bf16x8*)(zh + zo);
    al[kk] = *(const bf16x8*)(zl + zo);
  }
  int col16 = l & 15, rgrp = (l >> 4) * 4;
  for (int t = 0; t < NTYPES; ++t) {
    const ushort_t* bh0 = wkh + (size_t)t * (D * D);
    ushort_t* Pt = P + (size_t)t * n * D;
#pragma unroll
    for (int cp = 0; cp < 4; ++cp) {
      bf16x8 Bh[2][4];
#pragma unroll
      for (int cc = 0; cc < 2; ++cc)
#pragma unroll
        for (int kk = 0; kk < 4; ++kk) {
          size_t o = ((size_t)((cp * 2 + cc) * 4 + kk) * 64 + l) * 8;
          Bh[cc][kk] = *(const bf16x8*)(bh0 + o);
        }
      f32x4 aa[2], ac[2];
#pragma unroll
      for (int cc = 0; cc < 2; ++cc) {
        float bias = bk[t * D + (cp * 2 + cc) * 16 + col16];
        aa[cc] = (f32x4){bias, bias, bias, bias};
        ac[cc] = (f32x4){0.f, 0.f, 0.f, 0.f};
      }
#pragma unroll
      for (int kk = 0; kk < 4; ++kk)
#pragma unroll
        for (int cc = 0; cc < 2; ++cc) {
          aa[cc] = __builtin_amdgcn_mfma_f32_16x16x32_bf16(ah[kk], Bh[cc][kk], aa[cc], 0, 0, 0);
          ac[cc] = __builtin_amdgcn_mfma_f32_16x16x32_bf16(al[kk], Bh[cc][kk], ac[cc], 0, 0, 0);
        }
#pragma unroll
      for (int cc = 0; cc < 2; ++cc)
#pragma unroll
        for (int r = 0; r < 4; ++r) {
          int row = n0 + rgrp + r;
          if (row < n)
            Pt[(size_t)row * D + (cp * 2 + cc) * 16 + col16] =
                bfbits(aa[cc][r] + ac[cc][r]);
        }
    }
  }
}

// ---------------------------------------------------------------------------
// K3: typed-CSR build by (src, etype)
// ---------------------------------------------------------------------------
__global__ void zero_kernel(int* __restrict__ p, int n) {
  int i = blockIdx.x * 256 + threadIdx.x;
  if (i < n) p[i] = 0;
}

__global__ void hist5_kernel(const int* __restrict__ edges,
                             const unsigned char* __restrict__ masks,
                             const int* __restrict__ flag,
                             int* __restrict__ cnt5,
                             unsigned char* __restrict__ etype8, int E) {
  int e = blockIdx.x * 256 + threadIdx.x;
  if (e >= E) return;
  int t = decode_etype(masks, E, e, *flag);
  etype8[e] = (unsigned char)t;
  atomicAdd(&cnt5[edges[e] * 8 + t], 1);
}

__global__ __launch_bounds__(256) void scanA5_kernel(const int* __restrict__ cnt5,
                                                     int* __restrict__ loc,
                                                     int* __restrict__ bsums, int n) {
  __shared__ int ts[256];
  int tid = threadIdx.x;
  int i = blockIdx.x * 256 + tid;
  int v = 0;
  if (i < n) {
    int4 c0 = *(const int4*)(cnt5 + (size_t)i * 8);
    v = c0.x + c0.y + c0.z + c0.w + cnt5[(size_t)i * 8 + 4];
  }
  ts[tid] = v;
  __syncthreads();
  for (int o = 1; o < 256; o <<= 1) {
    int t = (tid >= o) ? ts[tid - o] : 0;
    __syncthreads();
    ts[tid] += t;
    __syncthreads();
  }
  if (i < n) loc[i] = ts[tid] - v;
  if (tid == 255) bsums[blockIdx.x] = ts[255];
}

__global__ __launch_bounds__(256) void scanB_kernel(int* __restrict__ bsums, int nb,
                                                    int* __restrict__ total) {
  __shared__ int ts[256];
  int tid = threadIdx.x;
  int per = (nb + 255) / 256;
  int start = tid * per;
  int end = min(start + per, nb);
  int s = 0;
  for (int i = start; i < end; ++i) s += bsums[i];
  ts[tid] = s;
  __syncthreads();
  for (int o = 1; o < 256; o <<= 1) {
    int t = (tid >= o) ? ts[tid - o] : 0;
    __syncthreads();
    ts[tid] += t;
    __syncthreads();
  }
  int run = ts[tid] - s;
  for (int i = start; i < end; ++i) {
    int v = bsums[i];
    bsums[i] = run;
    run += v;
  }
  if (tid == 255) *total = ts[255];
}

__global__ void scanC_kernel(const int* __restrict__ loc,
                             const int* __restrict__ bsums,
                             const int* __restrict__ total,
                             int* __restrict__ offs, int n) {
  int i = blockIdx.x * 256 + threadIdx.x;
  if (i < n) offs[i] = loc[i] + bsums[i >> 8];
  if (i == 0) offs[n] = *total;
}

__global__ void build5_kernel(const int* __restrict__ offs,
                              const int* __restrict__ cnt5,
                              int* __restrict__ cursor5, int* __restrict__ tb,
                              int n) {
  int i = blockIdx.x * 256 + threadIdx.x;
  if (i >= n) return;
  int base = offs[i];
#pragma unroll
  for (int t = 0; t < NTYPES; ++t) {
    int c = cnt5[(size_t)i * 8 + t];
    cursor5[(size_t)i * 8 + t] = base;
    tb[(size_t)i * 8 + t] = base;
    base += c;
  }
  tb[(size_t)i * 8 + 5] = base;
}

__global__ void fill_kernel(const int* __restrict__ edges,
                            const unsigned char* __restrict__ etype8,
                            int* __restrict__ cursor5,
                            int* __restrict__ elist, int E, int n) {
  int e = blockIdx.x * 256 + threadIdx.x;
  if (e >= E) return;
  int t = etype8[e];
  int dst = edges[E + e];
  int pos = atomicAdd(&cursor5[edges[e] * 8 + t], 1);
  elist[pos] = t * n + dst;
}

// ---------------------------------------------------------------------------
// K4: per-node attention over type-sorted runs. 16 lanes/node, 4 nodes/wave.
// ---------------------------------------------------------------------------
__global__ __launch_bounds__(256, 4) void attn_kernel(
    const float* __restrict__ x, const ushort_t* __restrict__ P,
    const int* __restrict__ tb, const int* __restrict__ elist,
    float* __restrict__ out, int n) {
  int node = (blockIdx.x * 256 + threadIdx.x) >> 4;
  int gl = threadIdx.x & 15;
  if (node >= n) return;

  int4 t03 = *(const int4*)(tb + (size_t)node * 8);
  int2 t45 = *(const int2*)(tb + (size_t)node * 8 + 4);
  int bnd0 = t03.x, bnd1 = t03.y, bnd2 = t03.z, bnd3 = t03.w;
  int bnd4 = t45.x, bnd5 = t45.y;

  float m = -1e30f, den = 0.f;
  float a[8];
#pragma unroll
  for (int i = 0; i < 8; ++i) a[i] = 0.f;

#pragma unroll
  for (int t = 0; t < NTYPES; ++t) {
    int jb = (t == 0) ? bnd0 : (t == 1) ? bnd1 : (t == 2) ? bnd2
             : (t == 3) ? bnd3 : bnd4;
    int je = (t == 0) ? bnd1 : (t == 1) ? bnd2 : (t == 2) ? bnd3
             : (t == 3) ? bnd4 : bnd5;
    if (jb >= je) continue;
    bf16x8 qb = *(const bf16x8*)(P + (size_t)(t * n + node) * D + gl * 8);
    float qf[8];
#pragma unroll
    for (int d = 0; d < 8; ++d) qf[d] = (float)qb[d];

    int row = elist[jb];
    bf16x8 kv = *(const bf16x8*)(P + (size_t)row * D + gl * 8);
    for (int j = jb; j < je; ++j) {
      bf16x8 kvn = kv;
      if (j + 1 < je) {
        int rn = elist[j + 1];
        kvn = *(const bf16x8*)(P + (size_t)rn * D + gl * 8);
      }
      float kf[8], p = 0.f;
#pragma unroll
      for (int d = 0; d < 8; ++d) {
        kf[d] = (float)kv[d];
        p += qf[d] * kf[d];
      }
      p += __shfl_xor(p, 1);  // 16 dims/head = 2 lanes
      float nm = fmaxf(m, p);
      float sc = __expf(m - nm);
      float w = __expf(p - nm);
      den = den * sc + w;
#pragma unroll
      for (int d = 0; d < 8; ++d) a[d] = a[d] * sc + w * kf[d];
      m = nm;
      kv = kvn;
    }
  }

  float inv = (bnd5 > bnd0) ? 1.f / den : 0.f;
  const float* xr = x + (size_t)node * D + gl * 8;
  float* orow = out + (size_t)node * D + gl * 8;
  float4 xa = *(const float4*)xr;
  float4 xb = *(const float4*)(xr + 4);
  float4 oa, ob;
  oa.x = xa.x + a[0] * inv; oa.y = xa.y + a[1] * inv;
  oa.z = xa.z + a[2] * inv; oa.w = xa.w + a[3] * inv;
  ob.x = xb.x + a[4] * inv; ob.y = xb.y + a[5] * inv;
  ob.z = xb.z + a[6] * inv; ob.w = xb.w + a[7] * inv;
  *(float4*)orow = oa;
  *(float4*)(orow + 4) = ob;
}

// ---------------------------------------------------------------------------
// K5: fused LN2 + FFN + residual via MFMA, in-place on out (holds x2).
// Occupancy-restructured: 32 rows/block, wave (r2,c2h) = (row-tile, col-half).
// GEMM1: wave computes its 16-hidden half-chunk; block-shared double-buffered
// bounce tile (one barrier/iter); GEMM2: wave owns 64 output cols.
// LDS 25KB, target 4 waves/SIMD.
// ---------------------------------------------------------------------------
__global__ __launch_bounds__(256, 4) void ffn_mfma_kernel(
    const ushort_t* __restrict__ w1h, const ushort_t* __restrict__ w2h,
    const float* __restrict__ b1, const float* __restrict__ b2,
    const float* __restrict__ g, const float* __restrict__ bln,
    float* __restrict__ out, int n) {
  __shared__ ushort_t z2h[32 * D];
  __shared__ ushort_t z2l[32 * D];
  __shared__ float hb2[2][2][16 * 36];  // [buf][row-tile][16 x 36]
  int tid = threadIdx.x, w = tid >> 6, l = tid & 63;
  int n0 = blockIdx.x * 32;
  int r2 = w >> 1, c2h = w & 1;

  // Phase 0: LN2 of 32 rows (4 waves x 8 rows), XOR-swizzled z2 hi/lo
  for (int i = w; i < 32; i += 4) {
    int r = n0 + i;
    float v0 = 0.f, v1 = 0.f;
    if (r < n) {
      v0 = out[(size_t)r * D + l];
      v1 = out[(size_t)r * D + 64 + l];
    }
    float s = v0 + v1, ss = v0 * v0 + v1 * v1;
    for (int o = 32; o; o >>= 1) { s += __shfl_xor(s, o); ss += __shfl_xor(ss, o); }
    float mu = s * (1.f / D);
    float var = ss * (1.f / D) - mu * mu;
    float rs = rsqrtf(var + LN_EPS);
    float z0 = (v0 - mu) * rs * g[l] + bln[l];
    float z1 = (v1 - mu) * rs * g[l + 64] + bln[l + 64];
    int sw = (i & 7) << 3;
    int e0 = (i * D + l) ^ sw;
    int e1 = (i * D + l + 64) ^ sw;
    __bf16 h0 = (__bf16)z0, h1 = (__bf16)z1;
    z2h[e0] = __builtin_bit_cast(ushort_t, h0);
    z2h[e1] = __builtin_bit_cast(ushort_t, h1);
    __bf16 l0 = (__bf16)(z0 - (float)h0), l1 = (__bf16)(z1 - (float)h1);
    z2l[e0] = __builtin_bit_cast(ushort_t, l0);
    z2l[e1] = __builtin_bit_cast(ushort_t, l1);
  }
  __syncthreads();

  // A-fragments of z2 for this wave's row-tile (16 rows)
  int lrow = r2 * 16 + (l & 15);
  int koff = (l >> 4) * 8;
  bf16x8 ah[4], al[4];
#pragma unroll
  for (int kk = 0; kk < 4; ++kk) {
    int e = (lrow * D + kk * 32 + koff) ^ ((lrow & 7) << 3);
    ah[kk] = *(const bf16x8*)(z2h + e);
    al[kk] = *(const bf16x8*)(z2l + e);
  }

  int col16 = l & 15, rgrp = (l >> 4) * 4;
  f32x4 acc2[4];
#pragma unroll
  for (int c = 0; c < 4; ++c) acc2[c] = (f32x4){0.f, 0.f, 0.f, 0.f};

  for (int kk2 = 0; kk2 < 16; ++kk2) {
    // ---- GEMM1: this wave's 16-hidden column tile c = kk2*2 + c2h
    int c = kk2 * 2 + c2h;
    bf16x8 B1h[4];
#pragma unroll
    for (int kk = 0; kk < 4; ++kk) {
      size_t o = ((size_t)(c * 4 + kk) * 64 + l) * 8;
      B1h[kk] = *(const bf16x8*)(w1h + o);
    }
    float bias = b1[c * 16 + col16];
    f32x4 ha = {bias, bias, bias, bias};
    f32x4 hc = {0.f, 0.f, 0.f, 0.f};
#pragma unroll
    for (int kk = 0; kk < 4; ++kk) {
      ha = __builtin_amdgcn_mfma_f32_16x16x32_bf16(ah[kk], B1h[kk], ha, 0, 0, 0);
      hc = __builtin_amdgcn_mfma_f32_16x16x32_bf16(al[kk], B1h[kk], hc, 0, 0, 0);
    }
    // ---- bounce: write this wave's hidden half into its row-tile's buffer
    float* hbp = &hb2[kk2 & 1][r2][0];
#pragma unroll
    for (int r = 0; r < 4; ++r)
      hbp[(rgrp + r) * 36 + c2h * 16 + col16] = fmaxf(ha[r] + hc[r], 0.f);
    __syncthreads();
    // ---- re-fragment: full 32-hidden chunk for this wave's row-tile
    float av[8];
    const float* hbr = &hb2[kk2 & 1][r2][0];
    *(float4*)&av[0] = *(const float4*)&hbr[(l & 15) * 36 + koff];
    *(float4*)&av[4] = *(const float4*)&hbr[(l & 15) * 36 + koff + 4];
    bf16x8 a2h, a2l;
#pragma unroll
    for (int j = 0; j < 8; ++j) {
      __bf16 hv = (__bf16)av[j];
      a2h[j] = hv;
      a2l[j] = (__bf16)(av[j] - (float)hv);
    }
    // ---- GEMM2: this wave's 4 output col-tiles (64 cols)
    bf16x8 B2h[4];
#pragma unroll
    for (int cc2 = 0; cc2 < 4; ++cc2) {
      int ct = c2h * 4 + cc2;
      size_t o = ((size_t)(ct * 16 + kk2) * 64 + l) * 8;
      B2h[cc2] = *(const bf16x8*)(w2h + o);
    }
#pragma unroll
    for (int cc2 = 0; cc2 < 4; ++cc2) {
      acc2[cc2] = __builtin_amdgcn_mfma_f32_16x16x32_bf16(a2h, B2h[cc2], acc2[cc2], 0, 0, 0);
      acc2[cc2] = __builtin_amdgcn_mfma_f32_16x16x32_bf16(a2l, B2h[cc2], acc2[cc2], 0, 0, 0);
    }
  }

  // Epilogue: out += ff + b2 (wave's 16 rows x 64 cols)
#pragma unroll
  for (int cc2 = 0; cc2 < 4; ++cc2) {
    int col = (c2h * 4 + cc2) * 16 + col16;
    float bias2 = b2[col];
#pragma unroll
    for (int r = 0; r < 4; ++r) {
      int row = n0 + r2 * 16 + rgrp + r;
      if (row < n) {
        size_t o = (size_t)row * D + col;
        out[o] = out[o] + acc2[cc2][r] + bias2;
      }
    }
  }
}

// ---------------------------------------------------------------------------
extern "C" void kernel_launch(void* const* d_in, const int* in_sizes, int n_in,
                              void* d_out, int out_size, void* d_ws, size_t ws_size,
                              hipStream_t stream) {
  const float* x      = (const float*)d_in[0];
  const int* edges    = (const int*)d_in[1];
  const unsigned char* masks = (const unsigned char*)d_in[2];
  const float* Wk     = (const float*)d_in[3];
  const float* bk     = (const float*)d_in[4];
  const float* ln1_g  = (const float*)d_in[5];
  const float* ln1_b  = (const float*)d_in[6];
  const float* ln2_g  = (const float*)d_in[7];
  const float* ln2_b  = (const float*)d_in[8];
  const float* W1     = (const float*)d_in[9];
  const float* b1     = (const float*)d_in[10];
  const float* W2     = (const float*)d_in[11];
  const float* b2     = (const float*)d_in[12];
  float* out = (float*)d_out;

  const int n = in_sizes[0] / D;
  const int E = in_sizes[1] / 2;
  const int nbn = (n + 255) / 256;  // scanA5 blocks (1 node/thread)

  // workspace layout (~74 MB)
  char* ws = (char*)d_ws;
  size_t off = 0;
  ushort_t* P = (ushort_t*)(ws + off);  off += (size_t)NTYPES * n * D * sizeof(ushort_t);
  int* cnt5   = (int*)(ws + off);       off += (size_t)n * 8 * sizeof(int);
  int* cursor5= (int*)(ws + off);       off += (size_t)n * 8 * sizeof(int);
  int* tb     = (int*)(ws + off);       off += (size_t)n * 8 * sizeof(int);
  int* offs   = (int*)(ws + off);       off += (size_t)(n + 1) * sizeof(int);
  int* loc    = (int*)(ws + off);       off += (size_t)n * sizeof(int);
  int* bsums  = (int*)(ws + off);       off += (size_t)nbn * sizeof(int);
  int* total  = (int*)(ws + off);       off += 64;
  int* elist  = (int*)(ws + off);       off += (size_t)E * sizeof(int);
  unsigned char* etype8 = (unsigned char*)(ws + off); off += (size_t)E + 64;
  int* flag   = (int*)(ws + off);       off += 64;
  ushort_t* wkh = (ushort_t*)(ws + off); off += (size_t)NTYPES * D * D * sizeof(ushort_t);
  ushort_t* w1h = (ushort_t*)(ws + off); off += (size_t)D * FFDIM * sizeof(ushort_t);
  ushort_t* w2h = (ushort_t*)(ws + off); off += (size_t)FFDIM * D * sizeof(ushort_t);
  (void)ws_size; (void)n_in; (void)out_size;

  // z hi/lo parked in d_out (dead before attn writes x2 there)
  ushort_t* zh = (ushort_t*)out;
  ushort_t* zl = zh + (size_t)n * D;

  // K0: mask dtype detection
  detect_kernel<<<1, 64, 0, stream>>>(masks, E, flag);

  // K1: LN1 -> z hi/lo
  ln1_kernel<<<(n + 3) / 4, 256, 0, stream>>>(x, ln1_g, ln1_b, zh, zl, n);

  // K1b: weight fragment conversion (hi only)
  {
    dim3 gwk((8 * 4 * 64 + 255) / 256, NTYPES);
    conv_frag_kernel<<<gwk, 256, 0, stream>>>(Wk, wkh, D, D,
                                              (size_t)D * D, (size_t)D * D);
    dim3 gw1(((FFDIM / 16) * 4 * 64 + 255) / 256, 1);
    conv_frag_kernel<<<gw1, 256, 0, stream>>>(W1, w1h, D, FFDIM, 0, 0);
    dim3 gw2((8 * (FFDIM / 32) * 64 + 255) / 256, 1);
    conv_frag_kernel<<<gw2, 256, 0, stream>>>(W2, w2h, FFDIM, D, 0, 0);
  }

  // K2: projections
  proj_mfma_kernel<<<(n + 63) / 64, 256, 0, stream>>>(zh, zl, wkh, bk, P, n);

  // K3: typed-CSR build
  zero_kernel<<<(n * 8 + 255) / 256, 256, 0, stream>>>(cnt5, n * 8);
  hist5_kernel<<<(E + 255) / 256, 256, 0, stream>>>(edges, masks, flag, cnt5, etype8, E);
  scanA5_kernel<<<nbn, 256, 0, stream>>>(cnt5, loc, bsums, n);
  scanB_kernel<<<1, 256, 0, stream>>>(bsums, nbn, total);
  scanC_kernel<<<(n + 255) / 256, 256, 0, stream>>>(loc, bsums, total, offs, n);
  build5_kernel<<<(n + 255) / 256, 256, 0, stream>>>(offs, cnt5, cursor5, tb, n);
  fill_kernel<<<(E + 255) / 256, 256, 0, stream>>>(edges, etype8, cursor5, elist, E, n);

  // K4: attention -> out = x + attn
  attn_kernel<<<(n + 15) / 16, 256, 0, stream>>>(x, P, tb, elist, out, n);

  // K5: LN2 + FFN + residual (32 rows/block)
  ffn_mfma_kernel<<<(n + 31) / 32, 256, 0, stream>>>(w1h, w2h,
                                                     b1, b2, ln2_g, ln2_b, out, n);
}

// Round 10
// 247.911 us; speedup vs baseline: 1.3569x; 1.0536x over previous
//
#include <hip/hip_runtime.h>

// Problem constants (match reference)
#define D 128
#define H 8
#define DK 16
#define FFDIM 512
#define NTYPES 5
#define LN_EPS 1e-5f

typedef __bf16 bf16x8 __attribute__((ext_vector_type(8)));
typedef float f32x4 __attribute__((ext_vector_type(4)));
typedef unsigned short ushort_t;
typedef unsigned int uint_t;

__device__ inline ushort_t bfbits(float f) {
  __bf16 b = (__bf16)f;
  return __builtin_bit_cast(ushort_t, b);
}

// ---------------------------------------------------------------------------
// K0: detect mask dtype (byte-bool vs int32). flag=1 for byte masks.
// ---------------------------------------------------------------------------
__global__ void detect_kernel(const unsigned char* __restrict__ m8, int E,
                              int* __restrict__ flag) {
  int lane = threadIdx.x;  // 64 threads, 1 wave
  int s = 1;
  if (lane < E) {
    s = 0;
#pragma unroll
    for (int i = 0; i < NTYPES; ++i) s += (m8[(size_t)i * E + lane] != 0);
  }
  unsigned long long b = __ballot(s == 1);
  if (lane == 0) *flag = (b == ~0ull) ? 1 : 0;
}

__device__ inline int decode_etype(const unsigned char* __restrict__ m8,
                                   int E, int e, int is8) {
  int t = 0;
  if (is8) {
#pragma unroll
    for (int i = 1; i < NTYPES; ++i) t += i * (m8[(size_t)i * E + e] != 0);
  } else {
    const int* m32 = (const int*)m8;
#pragma unroll
    for (int i = 1; i < NTYPES; ++i) t += i * (m32[(size_t)i * E + e] != 0);
  }
  return t > (NTYPES - 1) ? (NTYPES - 1) : t;
}

// ---------------------------------------------------------------------------
// K1: LayerNorm x -> z, stored as hi/lo bf16 split (parked in d_out)
// ---------------------------------------------------------------------------
__global__ __launch_bounds__(256) void ln1_kernel(
    const float* __restrict__ x, const float* __restrict__ g,
    const float* __restrict__ b, ushort_t* __restrict__ zh,
    ushort_t* __restrict__ zl, int n) {
  int row = blockIdx.x * 4 + (threadIdx.x >> 6);
  int lane = threadIdx.x & 63;
  if (row >= n) return;
  const float* xr = x + (size_t)row * D;
  float v0 = xr[lane], v1 = xr[lane + 64];
  float s = v0 + v1, ss = v0 * v0 + v1 * v1;
  for (int o = 32; o; o >>= 1) { s += __shfl_xor(s, o); ss += __shfl_xor(ss, o); }
  float mu = s * (1.f / D);
  float var = ss * (1.f / D) - mu * mu;
  float rs = rsqrtf(var + LN_EPS);
  float z0 = (v0 - mu) * rs * g[lane] + b[lane];
  float z1 = (v1 - mu) * rs * g[lane + 64] + b[lane + 64];
  size_t o0 = (size_t)row * D + lane, o1 = o0 + 64;
  __bf16 h0 = (__bf16)z0, h1 = (__bf16)z1;
  zh[o0] = __builtin_bit_cast(ushort_t, h0);
  zh[o1] = __builtin_bit_cast(ushort_t, h1);
  __bf16 l0 = (__bf16)(z0 - (float)h0), l1 = (__bf16)(z1 - (float)h1);
  zl[o0] = __builtin_bit_cast(ushort_t, l0);
  zl[o1] = __builtin_bit_cast(ushort_t, l1);
}

// ---------------------------------------------------------------------------
// K1b: convert a row-major f32 weight [K][N] into MFMA B-fragment order, bf16 hi.
// ---------------------------------------------------------------------------
__global__ void conv_frag_kernel(const float* __restrict__ W,
                                 ushort_t* __restrict__ hi,
                                 int K, int Ncol, size_t matW, size_t matF) {
  int gid = blockIdx.x * 256 + threadIdx.x;
  int total = (Ncol / 16) * (K / 32) * 64;
  if (gid >= total) return;
  const float* Wm = W + (size_t)blockIdx.y * matW;
  ushort_t* him = hi + (size_t)blockIdx.y * matF;
  int l = gid & 63;
  int ck = gid >> 6;
  int kk = ck % (K / 32);
  int c = ck / (K / 32);
  int row0 = kk * 32 + (l >> 4) * 8;
  int col = c * 16 + (l & 15);
  size_t ob = (size_t)gid * 8;
#pragma unroll
  for (int j = 0; j < 8; ++j) {
    float w = Wm[(size_t)(row0 + j) * Ncol + col];
    __bf16 h = (__bf16)w;
    him[ob + j] = __builtin_bit_cast(ushort_t, h);
  }
}

// ---------------------------------------------------------------------------
// K2: proj via MFMA: P[t][node][d] = bf16( (zh+zl) @ Wkh[t] + bk[t] )
// ---------------------------------------------------------------------------
__global__ __launch_bounds__(256, 3) void proj_mfma_kernel(
    const ushort_t* __restrict__ zh, const ushort_t* __restrict__ zl,
    const ushort_t* __restrict__ wkh,
    const float* __restrict__ bk, ushort_t* __restrict__ P, int n) {
  int w = threadIdx.x >> 6, l = threadIdx.x & 63;
  int n0 = blockIdx.x * 64 + w * 16;
  int arow = n0 + (l & 15);
  if (arow >= n) arow = n - 1;
  int koff = (l >> 4) * 8;
  bf16x8 ah[4], al[4];
#pragma unroll
  for (int kk = 0; kk < 4; ++kk) {
    size_t zo = (size_t)arow * D + kk * 32 + koff;
    ah[kk] = *(const bf16x8*)(zh + zo);
    al[kk] = *(const bf16x8*)(zl + zo);
  }
  int col16 = l & 15, rgrp = (l >> 4) * 4;
  for (int t = 0; t < NTYPES; ++t) {
    const ushort_t* bh0 = wkh + (size_t)t * (D * D);
    ushort_t* Pt = P + (size_t)t * n * D;
#pragma unroll
    for (int cp = 0; cp < 4; ++cp) {
      bf16x8 Bh[2][4];
#pragma unroll
      for (int cc = 0; cc < 2; ++cc)
#pragma unroll
        for (int kk = 0; kk < 4; ++kk) {
          size_t o = ((size_t)((cp * 2 + cc) * 4 + kk) * 64 + l) * 8;
          Bh[cc][kk] = *(const bf16x8*)(bh0 + o);
        }
      f32x4 aa[2], ac[2];
#pragma unroll
      for (int cc = 0; cc < 2; ++cc) {
        float bias = bk[t * D + (cp * 2 + cc) * 16 + col16];
        aa[cc] = (f32x4){bias, bias, bias, bias};
        ac[cc] = (f32x4){0.f, 0.f, 0.f, 0.f};
      }
#pragma unroll
      for (int kk = 0; kk < 4; ++kk)
#pragma unroll
        for (int cc = 0; cc < 2; ++cc) {
          aa[cc] = __builtin_amdgcn_mfma_f32_16x16x32_bf16(ah[kk], Bh[cc][kk], aa[cc], 0, 0, 0);
          ac[cc] = __builtin_amdgcn_mfma_f32_16x16x32_bf16(al[kk], Bh[cc][kk], ac[cc], 0, 0, 0);
        }
#pragma unroll
      for (int cc = 0; cc < 2; ++cc)
#pragma unroll
        for (int r = 0; r < 4; ++r) {
          int row = n0 + rgrp + r;
          if (row < n)
            Pt[(size_t)row * D + (cp * 2 + cc) * 16 + col16] =
                bfbits(aa[cc][r] + ac[cc][r]);
        }
    }
  }
}

// ---------------------------------------------------------------------------
// K3: typed-CSR build by (src, etype)
// ---------------------------------------------------------------------------
__global__ void zero_kernel(int* __restrict__ p, int n) {
  int i = blockIdx.x * 256 + threadIdx.x;
  if (i < n) p[i] = 0;
}

__global__ void hist5_kernel(const int* __restrict__ edges,
                             const unsigned char* __restrict__ masks,
                             const int* __restrict__ flag,
                             int* __restrict__ cnt5,
                             unsigned char* __restrict__ etype8, int E) {
  int e = blockIdx.x * 256 + threadIdx.x;
  if (e >= E) return;
  int t = decode_etype(masks, E, e, *flag);
  etype8[e] = (unsigned char)t;
  atomicAdd(&cnt5[edges[e] * 8 + t], 1);
}

__global__ __launch_bounds__(256) void scanA5_kernel(const int* __restrict__ cnt5,
                                                     int* __restrict__ loc,
                                                     int* __restrict__ bsums, int n) {
  __shared__ int ts[256];
  int tid = threadIdx.x;
  int i = blockIdx.x * 256 + tid;
  int v = 0;
  if (i < n) {
    int4 c0 = *(const int4*)(cnt5 + (size_t)i * 8);
    v = c0.x + c0.y + c0.z + c0.w + cnt5[(size_t)i * 8 + 4];
  }
  ts[tid] = v;
  __syncthreads();
  for (int o = 1; o < 256; o <<= 1) {
    int t = (tid >= o) ? ts[tid - o] : 0;
    __syncthreads();
    ts[tid] += t;
    __syncthreads();
  }
  if (i < n) loc[i] = ts[tid] - v;
  if (tid == 255) bsums[blockIdx.x] = ts[255];
}

__global__ __launch_bounds__(256) void scanB_kernel(int* __restrict__ bsums, int nb,
                                                    int* __restrict__ total) {
  __shared__ int ts[256];
  int tid = threadIdx.x;
  int per = (nb + 255) / 256;
  int start = tid * per;
  int end = min(start + per, nb);
  int s = 0;
  for (int i = start; i < end; ++i) s += bsums[i];
  ts[tid] = s;
  __syncthreads();
  for (int o = 1; o < 256; o <<= 1) {
    int t = (tid >= o) ? ts[tid - o] : 0;
    __syncthreads();
    ts[tid] += t;
    __syncthreads();
  }
  int run = ts[tid] - s;
  for (int i = start; i < end; ++i) {
    int v = bsums[i];
    bsums[i] = run;
    run += v;
  }
  if (tid == 255) *total = ts[255];
}

__global__ void scanC_kernel(const int* __restrict__ loc,
                             const int* __restrict__ bsums,
                             const int* __restrict__ total,
                             int* __restrict__ offs, int n) {
  int i = blockIdx.x * 256 + threadIdx.x;
  if (i < n) offs[i] = loc[i] + bsums[i >> 8];
  if (i == 0) offs[n] = *total;
}

__global__ void build5_kernel(const int* __restrict__ offs,
                              const int* __restrict__ cnt5,
                              int* __restrict__ cursor5, int* __restrict__ tb,
                              int n) {
  int i = blockIdx.x * 256 + threadIdx.x;
  if (i >= n) return;
  int base = offs[i];
#pragma unroll
  for (int t = 0; t < NTYPES; ++t) {
    int c = cnt5[(size_t)i * 8 + t];
    cursor5[(size_t)i * 8 + t] = base;
    tb[(size_t)i * 8 + t] = base;
    base += c;
  }
  tb[(size_t)i * 8 + 5] = base;
}

// fill: range-blocked + XCD-pinned scatter. range = blockIdx.x & 7 so that
// consecutive blocks (round-robin across the 8 XCDs) each own one node range;
// that range's elist slice (~E/8*4B) and cursor slice stay resident in ONE
// XCD's L2 and are written back once (kills 64B-line write amplification).
__global__ __launch_bounds__(256) void fill_kernel(
    const int* __restrict__ edges, const unsigned char* __restrict__ etype8,
    int* __restrict__ cursor5, int* __restrict__ elist, int E, int n) {
  int bx = blockIdx.x;
  int range = bx & 7;
  int e = (bx >> 3) * 256 + threadIdx.x;
  if (e >= E) return;
  int per = (n + 7) >> 3;
  int lo = range * per;
  int hi = min(lo + per, n);
  int src = edges[e];
  if (src < lo || src >= hi) return;
  int t = etype8[e];
  int dst = edges[E + e];
  int pos = atomicAdd(&cursor5[src * 8 + t], 1);
  elist[pos] = t * n + dst;
}

// ---------------------------------------------------------------------------
// K4: per-node attention over type-sorted runs. 16 lanes/node, 4 nodes/wave.
// ---------------------------------------------------------------------------
__global__ __launch_bounds__(256, 4) void attn_kernel(
    const float* __restrict__ x, const ushort_t* __restrict__ P,
    const int* __restrict__ tb, const int* __restrict__ elist,
    float* __restrict__ out, int n) {
  int node = (blockIdx.x * 256 + threadIdx.x) >> 4;
  int gl = threadIdx.x & 15;
  if (node >= n) return;

  int4 t03 = *(const int4*)(tb + (size_t)node * 8);
  int2 t45 = *(const int2*)(tb + (size_t)node * 8 + 4);
  int bnd0 = t03.x, bnd1 = t03.y, bnd2 = t03.z, bnd3 = t03.w;
  int bnd4 = t45.x, bnd5 = t45.y;

  float m = -1e30f, den = 0.f;
  float a[8];
#pragma unroll
  for (int i = 0; i < 8; ++i) a[i] = 0.f;

#pragma unroll
  for (int t = 0; t < NTYPES; ++t) {
    int jb = (t == 0) ? bnd0 : (t == 1) ? bnd1 : (t == 2) ? bnd2
             : (t == 3) ? bnd3 : bnd4;
    int je = (t == 0) ? bnd1 : (t == 1) ? bnd2 : (t == 2) ? bnd3
             : (t == 3) ? bnd4 : bnd5;
    if (jb >= je) continue;
    bf16x8 qb = *(const bf16x8*)(P + (size_t)(t * n + node) * D + gl * 8);
    float qf[8];
#pragma unroll
    for (int d = 0; d < 8; ++d) qf[d] = (float)qb[d];

    int row = elist[jb];
    bf16x8 kv = *(const bf16x8*)(P + (size_t)row * D + gl * 8);
    for (int j = jb; j < je; ++j) {
      bf16x8 kvn = kv;
      if (j + 1 < je) {
        int rn = elist[j + 1];
        kvn = *(const bf16x8*)(P + (size_t)rn * D + gl * 8);
      }
      float kf[8], p = 0.f;
#pragma unroll
      for (int d = 0; d < 8; ++d) {
        kf[d] = (float)kv[d];
        p += qf[d] * kf[d];
      }
      p += __shfl_xor(p, 1);  // 16 dims/head = 2 lanes
      float nm = fmaxf(m, p);
      float sc = __expf(m - nm);
      float w = __expf(p - nm);
      den = den * sc + w;
#pragma unroll
      for (int d = 0; d < 8; ++d) a[d] = a[d] * sc + w * kf[d];
      m = nm;
      kv = kvn;
    }
  }

  float inv = (bnd5 > bnd0) ? 1.f / den : 0.f;
  const float* xr = x + (size_t)node * D + gl * 8;
  float* orow = out + (size_t)node * D + gl * 8;
  float4 xa = *(const float4*)xr;
  float4 xb = *(const float4*)(xr + 4);
  float4 oa, ob;
  oa.x = xa.x + a[0] * inv; oa.y = xa.y + a[1] * inv;
  oa.z = xa.z + a[2] * inv; oa.w = xa.w + a[3] * inv;
  ob.x = xb.x + a[4] * inv; ob.y = xb.y + a[5] * inv;
  ob.z = xb.z + a[6] * inv; ob.w = xb.w + a[7] * inv;
  *(float4*)orow = oa;
  *(float4*)(orow + 4) = ob;
}

// ---------------------------------------------------------------------------
// K5: fused LN2 + FFN + residual via MFMA, in-place on out (holds x2).
// 32 rows/block, wave (r2,c2h) = (row-tile, col-half), double-buffered bounce.
// ---------------------------------------------------------------------------
__global__ __launch_bounds__(256, 4) void ffn_mfma_kernel(
    const ushort_t* __restrict__ w1h, const ushort_t* __restrict__ w2h,
    const float* __restrict__ b1, const float* __restrict__ b2,
    const float* __restrict__ g, const float* __restrict__ bln,
    float* __restrict__ out, int n) {
  __shared__ ushort_t z2h[32 * D];
  __shared__ ushort_t z2l[32 * D];
  __shared__ float hb2[2][2][16 * 36];  // [buf][row-tile][16 x 36]
  int tid = threadIdx.x, w = tid >> 6, l = tid & 63;
  int n0 = blockIdx.x * 32;
  int r2 = w >> 1, c2h = w & 1;

  for (int i = w; i < 32; i += 4) {
    int r = n0 + i;
    float v0 = 0.f, v1 = 0.f;
    if (r < n) {
      v0 = out[(size_t)r * D + l];
      v1 = out[(size_t)r * D + 64 + l];
    }
    float s = v0 + v1, ss = v0 * v0 + v1 * v1;
    for (int o = 32; o; o >>= 1) { s += __shfl_xor(s, o); ss += __shfl_xor(ss, o); }
    float mu = s * (1.f / D);
    float var = ss * (1.f / D) - mu * mu;
    float rs = rsqrtf(var + LN_EPS);
    float z0 = (v0 - mu) * rs * g[l] + bln[l];
    float z1 = (v1 - mu) * rs * g[l + 64] + bln[l + 64];
    int sw = (i & 7) << 3;
    int e0 = (i * D + l) ^ sw;
    int e1 = (i * D + l + 64) ^ sw;
    __bf16 h0 = (__bf16)z0, h1 = (__bf16)z1;
    z2h[e0] = __builtin_bit_cast(ushort_t, h0);
    z2h[e1] = __builtin_bit_cast(ushort_t, h1);
    __bf16 l0 = (__bf16)(z0 - (float)h0), l1 = (__bf16)(z1 - (float)h1);
    z2l[e0] = __builtin_bit_cast(ushort_t, l0);
    z2l[e1] = __builtin_bit_cast(ushort_t, l1);
  }
  __syncthreads();

  int lrow = r2 * 16 + (l & 15);
  int koff = (l >> 4) * 8;
  bf16x8 ah[4], al[4];
#pragma unroll
  for (int kk = 0; kk < 4; ++kk) {
    int e = (lrow * D + kk * 32 + koff) ^ ((lrow & 7) << 3);
    ah[kk] = *(const bf16x8*)(z2h + e);
    al[kk] = *(const bf16x8*)(z2l + e);
  }

  int col16 = l & 15, rgrp = (l >> 4) * 4;
  f32x4 acc2[4];
#pragma unroll
  for (int c = 0; c < 4; ++c) acc2[c] = (f32x4){0.f, 0.f, 0.f, 0.f};

  for (int kk2 = 0; kk2 < 16; ++kk2) {
    int c = kk2 * 2 + c2h;
    bf16x8 B1h[4];
#pragma unroll
    for (int kk = 0; kk < 4; ++kk) {
      size_t o = ((size_t)(c * 4 + kk) * 64 + l) * 8;
      B1h[kk] = *(const bf16x8*)(w1h + o);
    }
    float bias = b1[c * 16 + col16];
    f32x4 ha = {bias, bias, bias, bias};
    f32x4 hc = {0.f, 0.f, 0.f, 0.f};
#pragma unroll
    for (int kk = 0; kk < 4; ++kk) {
      ha = __builtin_amdgcn_mfma_f32_16x16x32_bf16(ah[kk], B1h[kk], ha, 0, 0, 0);
      hc = __builtin_amdgcn_mfma_f32_16x16x32_bf16(al[kk], B1h[kk], hc, 0, 0, 0);
    }
    float* hbp = &hb2[kk2 & 1][r2][0];
#pragma unroll
    for (int r = 0; r < 4; ++r)
      hbp[(rgrp + r) * 36 + c2h * 16 + col16] = fmaxf(ha[r] + hc[r], 0.f);
    __syncthreads();
    float av[8];
    const float* hbr = &hb2[kk2 & 1][r2][0];
    *(float4*)&av[0] = *(const float4*)&hbr[(l & 15) * 36 + koff];
    *(float4*)&av[4] = *(const float4*)&hbr[(l & 15) * 36 + koff + 4];
    bf16x8 a2h, a2l;
#pragma unroll
    for (int j = 0; j < 8; ++j) {
      __bf16 hv = (__bf16)av[j];
      a2h[j] = hv;
      a2l[j] = (__bf16)(av[j] - (float)hv);
    }
    bf16x8 B2h[4];
#pragma unroll
    for (int cc2 = 0; cc2 < 4; ++cc2) {
      int ct = c2h * 4 + cc2;
      size_t o = ((size_t)(ct * 16 + kk2) * 64 + l) * 8;
      B2h[cc2] = *(const bf16x8*)(w2h + o);
    }
#pragma unroll
    for (int cc2 = 0; cc2 < 4; ++cc2) {
      acc2[cc2] = __builtin_amdgcn_mfma_f32_16x16x32_bf16(a2h, B2h[cc2], acc2[cc2], 0, 0, 0);
      acc2[cc2] = __builtin_amdgcn_mfma_f32_16x16x32_bf16(a2l, B2h[cc2], acc2[cc2], 0, 0, 0);
    }
  }

#pragma unroll
  for (int cc2 = 0; cc2 < 4; ++cc2) {
    int col = (c2h * 4 + cc2) * 16 + col16;
    float bias2 = b2[col];
#pragma unroll
    for (int r = 0; r < 4; ++r) {
      int row = n0 + r2 * 16 + rgrp + r;
      if (row < n) {
        size_t o = (size_t)row * D + col;
        out[o] = out[o] + acc2[cc2][r] + bias2;
      }
    }
  }
}

// ---------------------------------------------------------------------------
extern "C" void kernel_launch(void* const* d_in, const int* in_sizes, int n_in,
                              void* d_out, int out_size, void* d_ws, size_t ws_size,
                              hipStream_t stream) {
  const float* x      = (const float*)d_in[0];
  const int* edges    = (const int*)d_in[1];
  const unsigned char* masks = (const unsigned char*)d_in[2];
  const float* Wk     = (const float*)d_in[3];
  const float* bk     = (const float*)d_in[4];
  const float* ln1_g  = (const float*)d_in[5];
  const float* ln1_b  = (const float*)d_in[6];
  const float* ln2_g  = (const float*)d_in[7];
  const float* ln2_b  = (const float*)d_in[8];
  const float* W1     = (const float*)d_in[9];
  const float* b1     = (const float*)d_in[10];
  const float* W2     = (const float*)d_in[11];
  const float* b2     = (const float*)d_in[12];
  float* out = (float*)d_out;

  const int n = in_sizes[0] / D;
  const int E = in_sizes[1] / 2;
  const int nbn = (n + 255) / 256;  // scanA5 blocks (1 node/thread)

  // workspace layout (~74 MB)
  char* ws = (char*)d_ws;
  size_t off = 0;
  ushort_t* P = (ushort_t*)(ws + off);  off += (size_t)NTYPES * n * D * sizeof(ushort_t);
  int* cnt5   = (int*)(ws + off);       off += (size_t)n * 8 * sizeof(int);
  int* cursor5= (int*)(ws + off);       off += (size_t)n * 8 * sizeof(int);
  int* tb     = (int*)(ws + off);       off += (size_t)n * 8 * sizeof(int);
  int* offs   = (int*)(ws + off);       off += (size_t)(n + 1) * sizeof(int);
  int* loc    = (int*)(ws + off);       off += (size_t)n * sizeof(int);
  int* bsums  = (int*)(ws + off);       off += (size_t)nbn * sizeof(int);
  int* total  = (int*)(ws + off);       off += 64;
  int* elist  = (int*)(ws + off);       off += (size_t)E * sizeof(int);
  unsigned char* etype8 = (unsigned char*)(ws + off); off += (size_t)E + 64;
  int* flag   = (int*)(ws + off);       off += 64;
  ushort_t* wkh = (ushort_t*)(ws + off); off += (size_t)NTYPES * D * D * sizeof(ushort_t);
  ushort_t* w1h = (ushort_t*)(ws + off); off += (size_t)D * FFDIM * sizeof(ushort_t);
  ushort_t* w2h = (ushort_t*)(ws + off); off += (size_t)FFDIM * D * sizeof(ushort_t);
  (void)ws_size; (void)n_in; (void)out_size;

  // z hi/lo parked in d_out (dead before attn writes x2 there)
  ushort_t* zh = (ushort_t*)out;
  ushort_t* zl = zh + (size_t)n * D;

  // K0: mask dtype detection
  detect_kernel<<<1, 64, 0, stream>>>(masks, E, flag);

  // K1: LN1 -> z hi/lo
  ln1_kernel<<<(n + 3) / 4, 256, 0, stream>>>(x, ln1_g, ln1_b, zh, zl, n);

  // K1b: weight fragment conversion (hi only)
  {
    dim3 gwk((8 * 4 * 64 + 255) / 256, NTYPES);
    conv_frag_kernel<<<gwk, 256, 0, stream>>>(Wk, wkh, D, D,
                                              (size_t)D * D, (size_t)D * D);
    dim3 gw1(((FFDIM / 16) * 4 * 64 + 255) / 256, 1);
    conv_frag_kernel<<<gw1, 256, 0, stream>>>(W1, w1h, D, FFDIM, 0, 0);
    dim3 gw2((8 * (FFDIM / 32) * 64 + 255) / 256, 1);
    conv_frag_kernel<<<gw2, 256, 0, stream>>>(W2, w2h, FFDIM, D, 0, 0);
  }

  // K2: projections
  proj_mfma_kernel<<<(n + 63) / 64, 256, 0, stream>>>(zh, zl, wkh, bk, P, n);

  // K3: typed-CSR build
  zero_kernel<<<(n * 8 + 255) / 256, 256, 0, stream>>>(cnt5, n * 8);
  hist5_kernel<<<(E + 255) / 256, 256, 0, stream>>>(edges, masks, flag, cnt5, etype8, E);
  scanA5_kernel<<<nbn, 256, 0, stream>>>(cnt5, loc, bsums, n);
  scanB_kernel<<<1, 256, 0, stream>>>(bsums, nbn, total);
  scanC_kernel<<<(n + 255) / 256, 256, 0, stream>>>(loc, bsums, total, offs, n);
  build5_kernel<<<(n + 255) / 256, 256, 0, stream>>>(offs, cnt5, cursor5, tb, n);
  // range-blocked, XCD-pinned fill: 8 ranges x E/256 chunks
  fill_kernel<<<((E + 255) / 256) * 8, 256, 0, stream>>>(edges, etype8, cursor5,
                                                         elist, E, n);

  // K4: attention -> out = x + attn
  attn_kernel<<<(n + 15) / 16, 256, 0, stream>>>(x, P, tb, elist, out, n);

  // K5: LN2 + FFN + residual (32 rows/block)
  ffn_mfma_kernel<<<(n + 31) / 32, 256, 0, stream>>>(w1h, w2h,
                                                     b1, b2, ln2_g, ln2_b, out, n);
}

// Round 11
// 239.228 us; speedup vs baseline: 1.4062x; 1.0363x over previous
//
#include <hip/hip_runtime.h>

// Problem constants (match reference)
#define D 128
#define H 8
#define DK 16
#define FFDIM 512
#define NTYPES 5
#define LN_EPS 1e-5f

typedef __bf16 bf16x8 __attribute__((ext_vector_type(8)));
typedef float f32x4 __attribute__((ext_vector_type(4)));
typedef unsigned short ushort_t;
typedef unsigned int uint_t;

__device__ inline ushort_t bfbits(float f) {
  __bf16 b = (__bf16)f;
  return __builtin_bit_cast(ushort_t, b);
}

// ---------------------------------------------------------------------------
// K0: detect mask dtype (byte-bool vs int32). flag=1 for byte masks.
// ---------------------------------------------------------------------------
__global__ void detect_kernel(const unsigned char* __restrict__ m8, int E,
                              int* __restrict__ flag) {
  int lane = threadIdx.x;  // 64 threads, 1 wave
  int s = 1;
  if (lane < E) {
    s = 0;
#pragma unroll
    for (int i = 0; i < NTYPES; ++i) s += (m8[(size_t)i * E + lane] != 0);
  }
  unsigned long long b = __ballot(s == 1);
  if (lane == 0) *flag = (b == ~0ull) ? 1 : 0;
}

__device__ inline int decode_etype(const unsigned char* __restrict__ m8,
                                   int E, int e, int is8) {
  int t = 0;
  if (is8) {
#pragma unroll
    for (int i = 1; i < NTYPES; ++i) t += i * (m8[(size_t)i * E + e] != 0);
  } else {
    const int* m32 = (const int*)m8;
#pragma unroll
    for (int i = 1; i < NTYPES; ++i) t += i * (m32[(size_t)i * E + e] != 0);
  }
  return t > (NTYPES - 1) ? (NTYPES - 1) : t;
}

// ---------------------------------------------------------------------------
// K1b: convert a row-major f32 weight [K][N] into MFMA B-fragment order, bf16 hi.
// ---------------------------------------------------------------------------
__global__ void conv_frag_kernel(const float* __restrict__ W,
                                 ushort_t* __restrict__ hi,
                                 int K, int Ncol, size_t matW, size_t matF) {
  int gid = blockIdx.x * 256 + threadIdx.x;
  int total = (Ncol / 16) * (K / 32) * 64;
  if (gid >= total) return;
  const float* Wm = W + (size_t)blockIdx.y * matW;
  ushort_t* him = hi + (size_t)blockIdx.y * matF;
  int l = gid & 63;
  int ck = gid >> 6;
  int kk = ck % (K / 32);
  int c = ck / (K / 32);
  int row0 = kk * 32 + (l >> 4) * 8;
  int col = c * 16 + (l & 15);
  size_t ob = (size_t)gid * 8;
#pragma unroll
  for (int j = 0; j < 8; ++j) {
    float w = Wm[(size_t)(row0 + j) * Ncol + col];
    __bf16 h = (__bf16)w;
    him[ob + j] = __builtin_bit_cast(ushort_t, h);
  }
}

// ---------------------------------------------------------------------------
// K2: fused LN1 + proj via MFMA.
// Block = 64 rows, 4 waves. LN of x -> hi/lo bf16 split in XOR-swizzled LDS,
// then P[t][node][d] = bf16( z @ Wkh[t] + bk[t] ) for all 5 types.
// Kills the z HBM round-trip and the separate LN1 dispatch.
// ---------------------------------------------------------------------------
__global__ __launch_bounds__(256, 4) void projln_kernel(
    const float* __restrict__ x, const float* __restrict__ g,
    const float* __restrict__ b, const ushort_t* __restrict__ wkh,
    const float* __restrict__ bk, ushort_t* __restrict__ P, int n) {
  __shared__ ushort_t zsh[64 * D];
  __shared__ ushort_t zsl[64 * D];
  int tid = threadIdx.x, w = tid >> 6, l = tid & 63;
  int n0 = blockIdx.x * 64;

  // Phase 0: LN1 of 64 rows into swizzled LDS (hi/lo split)
  for (int i = w; i < 64; i += 4) {
    int r = n0 + i;
    float v0 = 0.f, v1 = 0.f;
    if (r < n) {
      v0 = x[(size_t)r * D + l];
      v1 = x[(size_t)r * D + 64 + l];
    }
    float s = v0 + v1, ss = v0 * v0 + v1 * v1;
    for (int o = 32; o; o >>= 1) { s += __shfl_xor(s, o); ss += __shfl_xor(ss, o); }
    float mu = s * (1.f / D);
    float var = ss * (1.f / D) - mu * mu;
    float rs = rsqrtf(var + LN_EPS);
    float z0 = (v0 - mu) * rs * g[l] + b[l];
    float z1 = (v1 - mu) * rs * g[l + 64] + b[l + 64];
    int sw = (i & 7) << 3;
    int e0 = (i * D + l) ^ sw;
    int e1 = (i * D + l + 64) ^ sw;
    __bf16 h0 = (__bf16)z0, h1 = (__bf16)z1;
    zsh[e0] = __builtin_bit_cast(ushort_t, h0);
    zsh[e1] = __builtin_bit_cast(ushort_t, h1);
    __bf16 l0 = (__bf16)(z0 - (float)h0), l1 = (__bf16)(z1 - (float)h1);
    zsl[e0] = __builtin_bit_cast(ushort_t, l0);
    zsl[e1] = __builtin_bit_cast(ushort_t, l1);
  }
  __syncthreads();

  // A-fragments for this wave's 16 rows
  int lrow = w * 16 + (l & 15);
  int koff = (l >> 4) * 8;
  bf16x8 ah[4], al[4];
#pragma unroll
  for (int kk = 0; kk < 4; ++kk) {
    int e = (lrow * D + kk * 32 + koff) ^ ((lrow & 7) << 3);
    ah[kk] = *(const bf16x8*)(zsh + e);
    al[kk] = *(const bf16x8*)(zsl + e);
  }

  int col16 = l & 15, rgrp = (l >> 4) * 4;
  int rowbase = n0 + w * 16;
  for (int t = 0; t < NTYPES; ++t) {
    const ushort_t* bh0 = wkh + (size_t)t * (D * D);
    ushort_t* Pt = P + (size_t)t * n * D;
#pragma unroll
    for (int cp = 0; cp < 4; ++cp) {
      bf16x8 Bh[2][4];
#pragma unroll
      for (int cc = 0; cc < 2; ++cc)
#pragma unroll
        for (int kk = 0; kk < 4; ++kk) {
          size_t o = ((size_t)((cp * 2 + cc) * 4 + kk) * 64 + l) * 8;
          Bh[cc][kk] = *(const bf16x8*)(bh0 + o);
        }
      f32x4 aa[2], ac[2];
#pragma unroll
      for (int cc = 0; cc < 2; ++cc) {
        float bias = bk[t * D + (cp * 2 + cc) * 16 + col16];
        aa[cc] = (f32x4){bias, bias, bias, bias};
        ac[cc] = (f32x4){0.f, 0.f, 0.f, 0.f};
      }
#pragma unroll
      for (int kk = 0; kk < 4; ++kk)
#pragma unroll
        for (int cc = 0; cc < 2; ++cc) {
          aa[cc] = __builtin_amdgcn_mfma_f32_16x16x32_bf16(ah[kk], Bh[cc][kk], aa[cc], 0, 0, 0);
          ac[cc] = __builtin_amdgcn_mfma_f32_16x16x32_bf16(al[kk], Bh[cc][kk], ac[cc], 0, 0, 0);
        }
#pragma unroll
      for (int cc = 0; cc < 2; ++cc)
#pragma unroll
        for (int r = 0; r < 4; ++r) {
          int row = rowbase + rgrp + r;
          if (row < n)
            Pt[(size_t)row * D + (cp * 2 + cc) * 16 + col16] =
                bfbits(aa[cc][r] + ac[cc][r]);
        }
    }
  }
}

// ---------------------------------------------------------------------------
// K3: typed-CSR build by (src, etype)
// ---------------------------------------------------------------------------
__global__ void zero_kernel(int* __restrict__ p, int n) {
  int i = blockIdx.x * 256 + threadIdx.x;
  if (i < n) p[i] = 0;
}

__global__ void hist5_kernel(const int* __restrict__ edges,
                             const unsigned char* __restrict__ masks,
                             const int* __restrict__ flag,
                             int* __restrict__ cnt5,
                             unsigned char* __restrict__ etype8, int E) {
  int e = blockIdx.x * 256 + threadIdx.x;
  if (e >= E) return;
  int t = decode_etype(masks, E, e, *flag);
  etype8[e] = (unsigned char)t;
  atomicAdd(&cnt5[edges[e] * 8 + t], 1);
}

__global__ __launch_bounds__(256) void scanA5_kernel(const int* __restrict__ cnt5,
                                                     int* __restrict__ loc,
                                                     int* __restrict__ bsums, int n) {
  __shared__ int ts[256];
  int tid = threadIdx.x;
  int i = blockIdx.x * 256 + tid;
  int v = 0;
  if (i < n) {
    int4 c0 = *(const int4*)(cnt5 + (size_t)i * 8);
    v = c0.x + c0.y + c0.z + c0.w + cnt5[(size_t)i * 8 + 4];
  }
  ts[tid] = v;
  __syncthreads();
  for (int o = 1; o < 256; o <<= 1) {
    int t = (tid >= o) ? ts[tid - o] : 0;
    __syncthreads();
    ts[tid] += t;
    __syncthreads();
  }
  if (i < n) loc[i] = ts[tid] - v;
  if (tid == 255) bsums[blockIdx.x] = ts[255];
}

__global__ __launch_bounds__(256) void scanB_kernel(int* __restrict__ bsums, int nb,
                                                    int* __restrict__ total) {
  __shared__ int ts[256];
  int tid = threadIdx.x;
  int per = (nb + 255) / 256;
  int start = tid * per;
  int end = min(start + per, nb);
  int s = 0;
  for (int i = start; i < end; ++i) s += bsums[i];
  ts[tid] = s;
  __syncthreads();
  for (int o = 1; o < 256; o <<= 1) {
    int t = (tid >= o) ? ts[tid - o] : 0;
    __syncthreads();
    ts[tid] += t;
    __syncthreads();
  }
  int run = ts[tid] - s;
  for (int i = start; i < end; ++i) {
    int v = bsums[i];
    bsums[i] = run;
    run += v;
  }
  if (tid == 255) *total = ts[255];
}

// merged scanC+build5: offs computed inline from loc+bsums
__global__ void build5_kernel(const int* __restrict__ loc,
                              const int* __restrict__ bsums,
                              const int* __restrict__ cnt5,
                              int* __restrict__ cursor5, int* __restrict__ tb,
                              int n) {
  int i = blockIdx.x * 256 + threadIdx.x;
  if (i >= n) return;
  int base = loc[i] + bsums[i >> 8];
#pragma unroll
  for (int t = 0; t < NTYPES; ++t) {
    int c = cnt5[(size_t)i * 8 + t];
    cursor5[(size_t)i * 8 + t] = base;
    tb[(size_t)i * 8 + t] = base;
    base += c;
  }
  tb[(size_t)i * 8 + 5] = base;
}

// fill: range-blocked + XCD-pinned scatter (kills write amplification)
__global__ __launch_bounds__(256) void fill_kernel(
    const int* __restrict__ edges, const unsigned char* __restrict__ etype8,
    int* __restrict__ cursor5, int* __restrict__ elist, int E, int n) {
  int bx = blockIdx.x;
  int range = bx & 7;
  int e = (bx >> 3) * 256 + threadIdx.x;
  if (e >= E) return;
  int per = (n + 7) >> 3;
  int lo = range * per;
  int hi = min(lo + per, n);
  int src = edges[e];
  if (src < lo || src >= hi) return;
  int t = etype8[e];
  int dst = edges[E + e];
  int pos = atomicAdd(&cursor5[src * 8 + t], 1);
  elist[pos] = t * n + dst;
}

// ---------------------------------------------------------------------------
// K4: per-node attention over type-sorted runs. 16 lanes/node, 4 nodes/wave.
// ---------------------------------------------------------------------------
__global__ __launch_bounds__(256, 4) void attn_kernel(
    const float* __restrict__ x, const ushort_t* __restrict__ P,
    const int* __restrict__ tb, const int* __restrict__ elist,
    float* __restrict__ out, int n) {
  int node = (blockIdx.x * 256 + threadIdx.x) >> 4;
  int gl = threadIdx.x & 15;
  if (node >= n) return;

  int4 t03 = *(const int4*)(tb + (size_t)node * 8);
  int2 t45 = *(const int2*)(tb + (size_t)node * 8 + 4);
  int bnd0 = t03.x, bnd1 = t03.y, bnd2 = t03.z, bnd3 = t03.w;
  int bnd4 = t45.x, bnd5 = t45.y;

  float m = -1e30f, den = 0.f;
  float a[8];
#pragma unroll
  for (int i = 0; i < 8; ++i) a[i] = 0.f;

#pragma unroll
  for (int t = 0; t < NTYPES; ++t) {
    int jb = (t == 0) ? bnd0 : (t == 1) ? bnd1 : (t == 2) ? bnd2
             : (t == 3) ? bnd3 : bnd4;
    int je = (t == 0) ? bnd1 : (t == 1) ? bnd2 : (t == 2) ? bnd3
             : (t == 3) ? bnd4 : bnd5;
    if (jb >= je) continue;
    bf16x8 qb = *(const bf16x8*)(P + (size_t)(t * n + node) * D + gl * 8);
    float qf[8];
#pragma unroll
    for (int d = 0; d < 8; ++d) qf[d] = (float)qb[d];

    int row = elist[jb];
    bf16x8 kv = *(const bf16x8*)(P + (size_t)row * D + gl * 8);
    for (int j = jb; j < je; ++j) {
      bf16x8 kvn = kv;
      if (j + 1 < je) {
        int rn = elist[j + 1];
        kvn = *(const bf16x8*)(P + (size_t)rn * D + gl * 8);
      }
      float kf[8], p = 0.f;
#pragma unroll
      for (int d = 0; d < 8; ++d) {
        kf[d] = (float)kv[d];
        p += qf[d] * kf[d];
      }
      p += __shfl_xor(p, 1);  // 16 dims/head = 2 lanes
      float nm = fmaxf(m, p);
      float sc = __expf(m - nm);
      float w = __expf(p - nm);
      den = den * sc + w;
#pragma unroll
      for (int d = 0; d < 8; ++d) a[d] = a[d] * sc + w * kf[d];
      m = nm;
      kv = kvn;
    }
  }

  float inv = (bnd5 > bnd0) ? 1.f / den : 0.f;
  const float* xr = x + (size_t)node * D + gl * 8;
  float* orow = out + (size_t)node * D + gl * 8;
  float4 xa = *(const float4*)xr;
  float4 xb = *(const float4*)(xr + 4);
  float4 oa, ob;
  oa.x = xa.x + a[0] * inv; oa.y = xa.y + a[1] * inv;
  oa.z = xa.z + a[2] * inv; oa.w = xa.w + a[3] * inv;
  ob.x = xb.x + a[4] * inv; ob.y = xb.y + a[5] * inv;
  ob.z = xb.z + a[6] * inv; ob.w = xb.w + a[7] * inv;
  *(float4*)orow = oa;
  *(float4*)(orow + 4) = ob;
}

// ---------------------------------------------------------------------------
// K5: fused LN2 + FFN + residual via MFMA, in-place on out (holds x2).
// 32 rows/block; GEMM2 skewed one iteration behind GEMM1 so the 8 weight
// loads per segment fly under GEMM2(k-1)+GEMM1(k) compute before the
// barrier's vmcnt(0) drain.
// ---------------------------------------------------------------------------
__global__ __launch_bounds__(256, 4) void ffn_mfma_kernel(
    const ushort_t* __restrict__ w1h, const ushort_t* __restrict__ w2h,
    const float* __restrict__ b1, const float* __restrict__ b2,
    const float* __restrict__ g, const float* __restrict__ bln,
    float* __restrict__ out, int n) {
  __shared__ ushort_t z2h[32 * D];
  __shared__ ushort_t z2l[32 * D];
  __shared__ float hb2[2][2][16 * 36];  // [buf][row-tile][16 x 36]
  int tid = threadIdx.x, w = tid >> 6, l = tid & 63;
  int n0 = blockIdx.x * 32;
  int r2 = w >> 1, c2h = w & 1;

  // Phase 0: LN2 into swizzled LDS (hi/lo)
  for (int i = w; i < 32; i += 4) {
    int r = n0 + i;
    float v0 = 0.f, v1 = 0.f;
    if (r < n) {
      v0 = out[(size_t)r * D + l];
      v1 = out[(size_t)r * D + 64 + l];
    }
    float s = v0 + v1, ss = v0 * v0 + v1 * v1;
    for (int o = 32; o; o >>= 1) { s += __shfl_xor(s, o); ss += __shfl_xor(ss, o); }
    float mu = s * (1.f / D);
    float var = ss * (1.f / D) - mu * mu;
    float rs = rsqrtf(var + LN_EPS);
    float z0 = (v0 - mu) * rs * g[l] + bln[l];
    float z1 = (v1 - mu) * rs * g[l + 64] + bln[l + 64];
    int sw = (i & 7) << 3;
    int e0 = (i * D + l) ^ sw;
    int e1 = (i * D + l + 64) ^ sw;
    __bf16 h0 = (__bf16)z0, h1 = (__bf16)z1;
    z2h[e0] = __builtin_bit_cast(ushort_t, h0);
    z2h[e1] = __builtin_bit_cast(ushort_t, h1);
    __bf16 l0 = (__bf16)(z0 - (float)h0), l1 = (__bf16)(z1 - (float)h1);
    z2l[e0] = __builtin_bit_cast(ushort_t, l0);
    z2l[e1] = __builtin_bit_cast(ushort_t, l1);
  }
  __syncthreads();

  int lrow = r2 * 16 + (l & 15);
  int koff = (l >> 4) * 8;
  bf16x8 ah[4], al[4];
#pragma unroll
  for (int kk = 0; kk < 4; ++kk) {
    int e = (lrow * D + kk * 32 + koff) ^ ((lrow & 7) << 3);
    ah[kk] = *(const bf16x8*)(z2h + e);
    al[kk] = *(const bf16x8*)(z2l + e);
  }

  int col16 = l & 15, rgrp = (l >> 4) * 4;
  f32x4 acc2[4];
#pragma unroll
  for (int c = 0; c < 4; ++c) acc2[c] = (f32x4){0.f, 0.f, 0.f, 0.f};
  bf16x8 B2prev[4];

#pragma unroll
  for (int k = 0; k < 16; ++k) {
    // issue this iteration's weight loads (B1h used now, B2h used next iter)
    int c = k * 2 + c2h;
    bf16x8 B1h[4], B2h[4];
#pragma unroll
    for (int kk = 0; kk < 4; ++kk) {
      size_t o = ((size_t)(c * 4 + kk) * 64 + l) * 8;
      B1h[kk] = *(const bf16x8*)(w1h + o);
    }
#pragma unroll
    for (int cc2 = 0; cc2 < 4; ++cc2) {
      int ct = c2h * 4 + cc2;
      size_t o = ((size_t)(ct * 16 + k) * 64 + l) * 8;
      B2h[cc2] = *(const bf16x8*)(w2h + o);
    }
    // re-fragment previous chunk (written before last barrier)
    bf16x8 a2h, a2l;
    if (k > 0) {
      const float* hbr = &hb2[(k - 1) & 1][r2][0];
      float av[8];
      *(float4*)&av[0] = *(const float4*)&hbr[(l & 15) * 36 + koff];
      *(float4*)&av[4] = *(const float4*)&hbr[(l & 15) * 36 + koff + 4];
#pragma unroll
      for (int j = 0; j < 8; ++j) {
        __bf16 hv = (__bf16)av[j];
        a2h[j] = hv;
        a2l[j] = (__bf16)(av[j] - (float)hv);
      }
    }
    // GEMM1(k)
    float bias = b1[c * 16 + col16];
    f32x4 ha = {bias, bias, bias, bias};
    f32x4 hc = {0.f, 0.f, 0.f, 0.f};
#pragma unroll
    for (int kk = 0; kk < 4; ++kk) {
      ha = __builtin_amdgcn_mfma_f32_16x16x32_bf16(ah[kk], B1h[kk], ha, 0, 0, 0);
      hc = __builtin_amdgcn_mfma_f32_16x16x32_bf16(al[kk], B1h[kk], hc, 0, 0, 0);
    }
    float* hbp = &hb2[k & 1][r2][0];
#pragma unroll
    for (int r = 0; r < 4; ++r)
      hbp[(rgrp + r) * 36 + c2h * 16 + col16] = fmaxf(ha[r] + hc[r], 0.f);
    // GEMM2(k-1) — registers only, overlaps the in-flight loads
    if (k > 0) {
#pragma unroll
      for (int cc2 = 0; cc2 < 4; ++cc2) {
        acc2[cc2] = __builtin_amdgcn_mfma_f32_16x16x32_bf16(a2h, B2prev[cc2], acc2[cc2], 0, 0, 0);
        acc2[cc2] = __builtin_amdgcn_mfma_f32_16x16x32_bf16(a2l, B2prev[cc2], acc2[cc2], 0, 0, 0);
      }
    }
#pragma unroll
    for (int cc2 = 0; cc2 < 4; ++cc2) B2prev[cc2] = B2h[cc2];
    __syncthreads();
  }

  // epilogue: GEMM2(15)
  {
    const float* hbr = &hb2[1][r2][0];
    float av[8];
    *(float4*)&av[0] = *(const float4*)&hbr[(l & 15) * 36 + koff];
    *(float4*)&av[4] = *(const float4*)&hbr[(l & 15) * 36 + koff + 4];
    bf16x8 a2h, a2l;
#pragma unroll
    for (int j = 0; j < 8; ++j) {
      __bf16 hv = (__bf16)av[j];
      a2h[j] = hv;
      a2l[j] = (__bf16)(av[j] - (float)hv);
    }
#pragma unroll
    for (int cc2 = 0; cc2 < 4; ++cc2) {
      acc2[cc2] = __builtin_amdgcn_mfma_f32_16x16x32_bf16(a2h, B2prev[cc2], acc2[cc2], 0, 0, 0);
      acc2[cc2] = __builtin_amdgcn_mfma_f32_16x16x32_bf16(a2l, B2prev[cc2], acc2[cc2], 0, 0, 0);
    }
  }

#pragma unroll
  for (int cc2 = 0; cc2 < 4; ++cc2) {
    int col = (c2h * 4 + cc2) * 16 + col16;
    float bias2 = b2[col];
#pragma unroll
    for (int r = 0; r < 4; ++r) {
      int row = n0 + r2 * 16 + rgrp + r;
      if (row < n) {
        size_t o = (size_t)row * D + col;
        out[o] = out[o] + acc2[cc2][r] + bias2;
      }
    }
  }
}

// ---------------------------------------------------------------------------
extern "C" void kernel_launch(void* const* d_in, const int* in_sizes, int n_in,
                              void* d_out, int out_size, void* d_ws, size_t ws_size,
                              hipStream_t stream) {
  const float* x      = (const float*)d_in[0];
  const int* edges    = (const int*)d_in[1];
  const unsigned char* masks = (const unsigned char*)d_in[2];
  const float* Wk     = (const float*)d_in[3];
  const float* bk     = (const float*)d_in[4];
  const float* ln1_g  = (const float*)d_in[5];
  const float* ln1_b  = (const float*)d_in[6];
  const float* ln2_g  = (const float*)d_in[7];
  const float* ln2_b  = (const float*)d_in[8];
  const float* W1     = (const float*)d_in[9];
  const float* b1     = (const float*)d_in[10];
  const float* W2     = (const float*)d_in[11];
  const float* b2     = (const float*)d_in[12];
  float* out = (float*)d_out;

  const int n = in_sizes[0] / D;
  const int E = in_sizes[1] / 2;
  const int nbn = (n + 255) / 256;

  // workspace layout (~74 MB)
  char* ws = (char*)d_ws;
  size_t off = 0;
  ushort_t* P = (ushort_t*)(ws + off);  off += (size_t)NTYPES * n * D * sizeof(ushort_t);
  int* cnt5   = (int*)(ws + off);       off += (size_t)n * 8 * sizeof(int);
  int* cursor5= (int*)(ws + off);       off += (size_t)n * 8 * sizeof(int);
  int* tb     = (int*)(ws + off);       off += (size_t)n * 8 * sizeof(int);
  int* loc    = (int*)(ws + off);       off += (size_t)n * sizeof(int);
  int* bsums  = (int*)(ws + off);       off += (size_t)nbn * sizeof(int);
  int* total  = (int*)(ws + off);       off += 64;
  int* elist  = (int*)(ws + off);       off += (size_t)E * sizeof(int);
  unsigned char* etype8 = (unsigned char*)(ws + off); off += (size_t)E + 64;
  int* flag   = (int*)(ws + off);       off += 64;
  ushort_t* wkh = (ushort_t*)(ws + off); off += (size_t)NTYPES * D * D * sizeof(ushort_t);
  ushort_t* w1h = (ushort_t*)(ws + off); off += (size_t)D * FFDIM * sizeof(ushort_t);
  ushort_t* w2h = (ushort_t*)(ws + off); off += (size_t)FFDIM * D * sizeof(ushort_t);
  (void)ws_size; (void)n_in; (void)out_size;

  // K0: mask dtype detection
  detect_kernel<<<1, 64, 0, stream>>>(masks, E, flag);

  // K1b: weight fragment conversion (hi only)
  {
    dim3 gwk((8 * 4 * 64 + 255) / 256, NTYPES);
    conv_frag_kernel<<<gwk, 256, 0, stream>>>(Wk, wkh, D, D,
                                              (size_t)D * D, (size_t)D * D);
    dim3 gw1(((FFDIM / 16) * 4 * 64 + 255) / 256, 1);
    conv_frag_kernel<<<gw1, 256, 0, stream>>>(W1, w1h, D, FFDIM, 0, 0);
    dim3 gw2((8 * (FFDIM / 32) * 64 + 255) / 256, 1);
    conv_frag_kernel<<<gw2, 256, 0, stream>>>(W2, w2h, FFDIM, D, 0, 0);
  }

  // K2: fused LN1 + projections
  projln_kernel<<<(n + 63) / 64, 256, 0, stream>>>(x, ln1_g, ln1_b, wkh, bk, P, n);

  // K3: typed-CSR build
  zero_kernel<<<(n * 8 + 255) / 256, 256, 0, stream>>>(cnt5, n * 8);
  hist5_kernel<<<(E + 255) / 256, 256, 0, stream>>>(edges, masks, flag, cnt5, etype8, E);
  scanA5_kernel<<<nbn, 256, 0, stream>>>(cnt5, loc, bsums, n);
  scanB_kernel<<<1, 256, 0, stream>>>(bsums, nbn, total);
  build5_kernel<<<(n + 255) / 256, 256, 0, stream>>>(loc, bsums, cnt5, cursor5, tb, n);
  fill_kernel<<<((E + 255) / 256) * 8, 256, 0, stream>>>(edges, etype8, cursor5,
                                                         elist, E, n);

  // K4: attention -> out = x + attn
  attn_kernel<<<(n + 15) / 16, 256, 0, stream>>>(x, P, tb, elist, out, n);

  // K5: LN2 + FFN + residual (32 rows/block, pipelined)
  ffn_mfma_kernel<<<(n + 31) / 32, 256, 0, stream>>>(w1h, w2h,
                                                     b1, b2, ln2_g, ln2_b, out, n);
}